// Round 1
// baseline (279.920 us; speedup 1.0000x reference)
//
#include <hip/hip_runtime.h>
#include <math.h>

#define DD 768
#define SS 50
#define TT 5
#define BB 512
#define EE 128
#define CC 10

// ---------------- kernel 0: fuse conv_W and cross_w into Wall[768][20] ----------------
__global__ void k_fusew(const float* __restrict__ Wconv, const float* __restrict__ Wcross,
                        float* __restrict__ Wall) {
    int i = blockIdx.x * 256 + threadIdx.x;  // over 768*20
    if (i >= DD * 20) return;
    int d = i / 20, c = i % 20;
    Wall[i] = (c < 10) ? Wconv[d * 10 + c] : Wcross[d * 10 + (c - 10)];
}

// ---------------- kernel 1: gathered token matvec h[tok][20] = emb[tok] @ Wall ----------------
// block = 128 threads = 2 waves; each wave owns 64 tokens (lane = token).
// Per 64-d chunk: stage rows coalesced into LDS [64][65] (pad -> conflict-free reads),
// then each lane does its own matvec; W via uniform (scalar) loads.
__global__ __launch_bounds__(128) void k_tokmv(const int* __restrict__ tokens, int ntok,
                                               const float* __restrict__ emb,
                                               const float* __restrict__ Wall,
                                               float* __restrict__ out) {
    __shared__ float tile[2][64][65];
    __shared__ int rowid[2][64];
    const int wv = threadIdx.x >> 6, lane = threadIdx.x & 63;
    const int base = blockIdx.x * 128 + wv * 64;
    const int tIdx = base + lane;
    int tok = 0;
    if (tIdx < ntok) tok = tokens[tIdx];
    rowid[wv][lane] = tok;
    __syncthreads();

    float acc[20];
#pragma unroll
    for (int c = 0; c < 20; c++) acc[c] = 0.f;
    const int g4 = lane >> 4, m = lane & 15;

    for (int chunk = 0; chunk < 12; ++chunk) {
        const int d0 = chunk * 64;
        // stage 64 tokens x 64 d, float4 per lane, 4 tokens per iteration
#pragma unroll
        for (int it = 0; it < 16; ++it) {
            int ti = it * 4 + g4;
            long r = rowid[wv][ti];
            const float4 v = *(const float4*)(emb + r * DD + d0 + m * 4);
            tile[wv][ti][m * 4 + 0] = v.x;
            tile[wv][ti][m * 4 + 1] = v.y;
            tile[wv][ti][m * 4 + 2] = v.z;
            tile[wv][ti][m * 4 + 3] = v.w;
        }
        __syncthreads();
#pragma unroll 4
        for (int d = 0; d < 64; ++d) {
            float e = tile[wv][lane][d];
            const float* w = Wall + (d0 + d) * 20;  // uniform address -> scalar loads
#pragma unroll
            for (int c = 0; c < 20; c++) acc[c] = fmaf(e, w[c], acc[c]);
        }
        __syncthreads();
    }
    if (tIdx < ntok) {
        float* o = out + (long)tIdx * 20;
#pragma unroll
        for (int c = 0; c < 20; c++) o[c] = acc[c];
    }
}

// ---------------- kernel 2a: response graphs -> resp_gcn[B][50][10], u_cross[B][50][10] ----------------
__global__ __launch_bounds__(64) void k_resp(const float* __restrict__ h,   // [B][50][20]
                                             const int* __restrict__ adj,   // [B][2][128]
                                             const float* __restrict__ conv_b,
                                             const float* __restrict__ att, // [50][50]
                                             float* __restrict__ gcn_out,
                                             float* __restrict__ cross_out) {
    __shared__ float hs[SS][20];
    __shared__ int esrc[EE], edst[EE];
    __shared__ float enorm[EE];
    __shared__ int degi[SS];
    __shared__ float dinv[SS];
    const int b = blockIdx.x, lane = threadIdx.x;
    const float* hb = h + (long)b * SS * 20;
    for (int i = lane; i < SS * 20; i += 64) ((float*)hs)[i] = hb[i];
    const int* ab = adj + (long)b * 2 * EE;
    if (lane < SS) degi[lane] = 1;  // self loop
    for (int e = lane; e < EE; e += 64) { esrc[e] = ab[e]; edst[e] = ab[EE + e]; }
    __syncthreads();
    for (int e = lane; e < EE; e += 64) atomicAdd(&degi[edst[e]], 1);
    __syncthreads();
    if (lane < SS) dinv[lane] = 1.0f / sqrtf(fmaxf((float)degi[lane], 1e-12f));
    __syncthreads();
    for (int e = lane; e < EE; e += 64) enorm[e] = dinv[esrc[e]] * dinv[edst[e]];
    __syncthreads();

    const int p = lane;
    if (p < SS) {
        // GCN: deterministic lane-owns-destination scan
        float acc[CC];
        float dp2 = dinv[p] * dinv[p];
#pragma unroll
        for (int c = 0; c < CC; c++) acc[c] = hs[p][c] * dp2 + conv_b[c];
        for (int e = 0; e < EE; e++) {
            if (edst[e] == p) {
                float nm = enorm[e];
                int s = esrc[e];
#pragma unroll
                for (int c = 0; c < CC; c++) acc[c] = fmaf(hs[s][c], nm, acc[c]);
            }
        }
        float* go = gcn_out + ((long)b * SS + p) * CC;
#pragma unroll
        for (int c = 0; c < CC; c++) go[c] = acc[c];
        // cross: att @ h_cross
        float ax[CC];
#pragma unroll
        for (int c = 0; c < CC; c++) ax[c] = 0.f;
        for (int s = 0; s < SS; s++) {
            float a = att[p * SS + s];
#pragma unroll
            for (int c = 0; c < CC; c++) ax[c] = fmaf(a, hs[s][10 + c], ax[c]);
        }
        float* xo = cross_out + ((long)b * SS + p) * CC;
#pragma unroll
        for (int c = 0; c < CC; c++) xo[c] = ax[c];
    }
}

// ---------------- kernel 2b: utterance graphs + both mpm calls -> g_u, g_r [B*T][20] ----------------
__global__ __launch_bounds__(64) void k_utt(const float* __restrict__ h,    // [B*T][50][20]
                                            const int* __restrict__ adj,    // [B*T][2][128]
                                            const float* __restrict__ conv_b,
                                            const float* __restrict__ att,
                                            const float* __restrict__ assign,  // [50][10]
                                            const float* __restrict__ W1, const float* __restrict__ b1,
                                            const float* __restrict__ W2, const float* __restrict__ b2,
                                            const float* __restrict__ resp_gcn, // [B][50][10]
                                            const float* __restrict__ u_cross,  // [B][50][10]
                                            float* __restrict__ g_u,
                                            float* __restrict__ g_r) {
    __shared__ float hs[SS][20];
    __shared__ int esrc[EE], edst[EE];
    __shared__ float enorm[EE];
    __shared__ int degi[SS];
    __shared__ float dinv[SS];
    __shared__ float sg[SS][CC];   // ctx gcn
    __shared__ float xr[SS][CC];   // r_cross
    __shared__ float sr[SS][CC];   // resp gcn
    __shared__ float xu[SS][CC];   // u_cross
    __shared__ float asg[SS][CC];  // assign
    const int g = blockIdx.x;
    const int b = g / TT;
    const int lane = threadIdx.x;

    const float* hb = h + (long)g * SS * 20;
    for (int i = lane; i < SS * 20; i += 64) ((float*)hs)[i] = hb[i];
    const int* ab = adj + (long)g * 2 * EE;
    if (lane < SS) degi[lane] = 1;
    for (int e = lane; e < EE; e += 64) { esrc[e] = ab[e]; edst[e] = ab[EE + e]; }
    for (int i = lane; i < SS * CC; i += 64) {
        ((float*)sr)[i] = resp_gcn[(long)b * SS * CC + i];
        ((float*)xu)[i] = u_cross[(long)b * SS * CC + i];
        ((float*)asg)[i] = assign[i];
    }
    __syncthreads();
    for (int e = lane; e < EE; e += 64) atomicAdd(&degi[edst[e]], 1);
    __syncthreads();
    if (lane < SS) dinv[lane] = 1.0f / sqrtf(fmaxf((float)degi[lane], 1e-12f));
    __syncthreads();
    for (int e = lane; e < EE; e += 64) enorm[e] = dinv[esrc[e]] * dinv[edst[e]];
    __syncthreads();

    const int p = lane;
    if (p < SS) {
        float acc[CC];
        float dp2 = dinv[p] * dinv[p];
#pragma unroll
        for (int c = 0; c < CC; c++) acc[c] = hs[p][c] * dp2 + conv_b[c];
        for (int e = 0; e < EE; e++) {
            if (edst[e] == p) {
                float nm = enorm[e];
                int s = esrc[e];
#pragma unroll
                for (int c = 0; c < CC; c++) acc[c] = fmaf(hs[s][c], nm, acc[c]);
            }
        }
#pragma unroll
        for (int c = 0; c < CC; c++) sg[p][c] = acc[c];
        float ax[CC];
#pragma unroll
        for (int c = 0; c < CC; c++) ax[c] = 0.f;
        for (int s = 0; s < SS; s++) {
            float a = att[p * SS + s];
#pragma unroll
            for (int c = 0; c < CC; c++) ax[c] = fmaf(a, hs[s][10 + c], ax[c]);
        }
#pragma unroll
        for (int c = 0; c < CC; c++) xr[p][c] = ax[c];
    }
    __syncthreads();

    // mpm twice: which==0 -> g_u: self=ctx_gcn(sg), cross=u_cross(xu)
    //            which==1 -> g_r: self=resp_gcn(sr), cross=r_cross(xr)
    for (int which = 0; which < 2; ++which) {
        const float(*sf)[CC] = which ? sr : sg;
        const float(*cf)[CC] = which ? xr : xu;
        float h2[20];
        if (lane < SS) {
            const int s = lane;
            float num = 0.f, na = 0.f, nc2 = 0.f;
#pragma unroll
            for (int c = 0; c < CC; c++) {
                float av = asg[s][c];
                float a = av * sf[s][c];
                float cx = av * cf[s][c];
                num = fmaf(a, cx, num);
                na = fmaf(a, a, na);
                nc2 = fmaf(cx, cx, nc2);
            }
            float cosv = num / fmaxf(sqrtf(na) * sqrtf(nc2), 1e-8f);
            float h1[20];
#pragma unroll
            for (int j = 0; j < 20; j++) h1[j] = fmaf(cosv, W1[j], b1[j]);
#pragma unroll
            for (int k = 0; k < CC; k++) {
                float sv = sf[s][k];
#pragma unroll
                for (int j = 0; j < 20; j++) h1[j] = fmaf(sv, W1[(k + 1) * 20 + j], h1[j]);
            }
#pragma unroll
            for (int j = 0; j < 20; j++) h1[j] = fmaxf(h1[j], 0.f);
#pragma unroll
            for (int j = 0; j < 20; j++) {
                float t = b2[j];
#pragma unroll
                for (int k = 0; k < 20; k++) t = fmaf(h1[k], W2[k * 20 + j], t);
                h2[j] = t;
            }
        } else {
#pragma unroll
            for (int j = 0; j < 20; j++) h2[j] = -1e30f;
        }
        // max over nodes (lanes)
        for (int off = 32; off; off >>= 1) {
#pragma unroll
            for (int j = 0; j < 20; j++) h2[j] = fmaxf(h2[j], __shfl_xor(h2[j], off));
        }
        if (lane == 0) {
            float* o = (which ? g_r : g_u) + (long)g * 20;
#pragma unroll
            for (int j = 0; j < 20; j++) o[j] = h2[j];
        }
    }
}

// ---------------- kernel 3: final FFN + sum over T + sigmoid ----------------
__global__ __launch_bounds__(64) void k_final(const float* __restrict__ g_u, const float* __restrict__ g_r,
                                              const float* __restrict__ W1, const float* __restrict__ b1,
                                              const float* __restrict__ W2, const float* __restrict__ b2,
                                              float* __restrict__ out) {
    const int b = blockIdx.x, lane = threadIdx.x;
    float ssum = 0.f;
    for (int t = 0; t < TT; t++) {
        const float* gu = g_u + ((long)b * TT + t) * 20;
        const float* gr = g_r + ((long)b * TT + t) * 20;
        float feat[80];
#pragma unroll
        for (int k = 0; k < 20; k++) {
            float u = gu[k], r = gr[k];
            feat[k] = u;
            feat[20 + k] = r;
            feat[40 + k] = u * r;
            feat[60 + k] = fabsf(u - r);
        }
        if (lane < 40) {
            float hv = b1[lane];
#pragma unroll
            for (int k = 0; k < 80; k++) hv = fmaf(feat[k], W1[k * 40 + lane], hv);
            ssum += fmaxf(hv, 0.f) * W2[lane];
        }
    }
    for (int off = 32; off; off >>= 1) ssum += __shfl_xor(ssum, off);
    if (lane == 0) out[b] = 1.f / (1.f + expf(-(ssum + (float)TT * b2[0])));
}

extern "C" void kernel_launch(void* const* d_in, const int* in_sizes, int n_in,
                              void* d_out, int out_size, void* d_ws, size_t ws_size,
                              hipStream_t stream) {
    (void)in_sizes; (void)n_in; (void)out_size; (void)ws_size;
    const int* ctx_tok = (const int*)d_in[0];
    const int* resp_tok = (const int*)d_in[1];
    const int* ctx_adj = (const int*)d_in[2];
    const int* resp_adj = (const int*)d_in[3];
    const float* emb = (const float*)d_in[4];
    const float* convW = (const float*)d_in[5];
    const float* convb = (const float*)d_in[6];
    const float* crossW = (const float*)d_in[7];
    const float* att = (const float*)d_in[8];
    const float* assign = (const float*)d_in[9];
    const float* mpW1 = (const float*)d_in[10];
    const float* mpb1 = (const float*)d_in[11];
    const float* mpW2 = (const float*)d_in[12];
    const float* mpb2 = (const float*)d_in[13];
    const float* fW1 = (const float*)d_in[14];
    const float* fb1 = (const float*)d_in[15];
    const float* fW2 = (const float*)d_in[16];
    const float* fb2 = (const float*)d_in[17];

    float* ws = (float*)d_ws;
    float* Wall = ws;                       // 15,360
    float* h_ctx = Wall + 15360;            // 2,560,000  [B*T*S][20]
    float* h_resp = h_ctx + 2560000;        // 512,000    [B*S][20]
    float* rgcn = h_resp + 512000;          // 256,000    [B][50][10]
    float* ucx = rgcn + 256000;             // 256,000    [B][50][10]
    float* gu = ucx + 256000;               // 51,200     [B*T][20]
    float* gr = gu + 51200;                 // 51,200
    float* outf = (float*)d_out;

    hipLaunchKernelGGL(k_fusew, dim3(60), dim3(256), 0, stream, convW, crossW, Wall);
    hipLaunchKernelGGL(k_tokmv, dim3(1000), dim3(128), 0, stream, ctx_tok, BB * TT * SS, emb, Wall, h_ctx);
    hipLaunchKernelGGL(k_tokmv, dim3(200), dim3(128), 0, stream, resp_tok, BB * SS, emb, Wall, h_resp);
    hipLaunchKernelGGL(k_resp, dim3(BB), dim3(64), 0, stream, h_resp, resp_adj, convb, att, rgcn, ucx);
    hipLaunchKernelGGL(k_utt, dim3(BB * TT), dim3(64), 0, stream, h_ctx, ctx_adj, convb, att, assign,
                       mpW1, mpb1, mpW2, mpb2, rgcn, ucx, gu, gr);
    hipLaunchKernelGGL(k_final, dim3(BB), dim3(64), 0, stream, gu, gr, fW1, fb1, fW2, fb2, outf);
}

// Round 2
// 181.775 us; speedup vs baseline: 1.5399x; 1.5399x over previous
//
#include <hip/hip_runtime.h>
#include <math.h>

#define VOCAB 21128
#define DD 768
#define SS 50
#define TT 5
#define BB 512
#define EE 128
#define CC 10

// ---------------- kernel 0: fuse conv_W and cross_w into Wall[768][20] ----------------
__global__ void k_fusew(const float* __restrict__ Wconv, const float* __restrict__ Wcross,
                        float* __restrict__ Wall) {
    int i = blockIdx.x * 256 + threadIdx.x;  // over 768*20
    if (i >= DD * 20) return;
    int d = i / 20, c = i % 20;
    Wall[i] = (c < 10) ? Wconv[d * 10 + c] : Wcross[d * 10 + (c - 10)];
}

// ---------------- kernel 1: hvocab[21128][20] = emb @ Wall ----------------
// 331 blocks x 256 threads (4 waves). Wave wv handles d-part [wv*192, wv*192+192)
// for the SAME 64 rows; 3 chunks of 64 d each: stage coalesced into LDS [64][65],
// lane = row, W via wave-uniform scalar loads. Deterministic cross-wave LDS reduce.
__global__ __launch_bounds__(256) void k_vocab(const float* __restrict__ emb,
                                               const float* __restrict__ Wall,
                                               float* __restrict__ hv) {
    __shared__ float tile[4][64][65];  // 66.6 KB -> 2 blocks/CU
    const int wv = threadIdx.x >> 6, lane = threadIdx.x & 63;
    const int rowbase = blockIdx.x * 64;
    const int g4 = lane >> 4, m = lane & 15;

    float acc[20];
#pragma unroll
    for (int c = 0; c < 20; c++) acc[c] = 0.f;

    for (int chunk = 0; chunk < 3; ++chunk) {
        const int d0 = wv * 192 + chunk * 64;  // wave-uniform
        // stage 64 rows x 64 d, coalesced: 16 lanes read 256B contiguous per row
#pragma unroll
        for (int it = 0; it < 16; ++it) {
            int ti = it * 4 + g4;
            long r = rowbase + ti;
            if (r >= VOCAB) r = VOCAB - 1;
            const float4 v = *(const float4*)(emb + r * DD + d0 + m * 4);
            tile[wv][ti][m * 4 + 0] = v.x;
            tile[wv][ti][m * 4 + 1] = v.y;
            tile[wv][ti][m * 4 + 2] = v.z;
            tile[wv][ti][m * 4 + 3] = v.w;
        }
        __syncthreads();
#pragma unroll 4
        for (int d = 0; d < 64; ++d) {
            float e = tile[wv][lane][d];
            const float* w = Wall + (d0 + d) * 20;  // uniform -> scalar loads
#pragma unroll
            for (int c = 0; c < 20; c++) acc[c] = fmaf(e, w[c], acc[c]);
        }
        __syncthreads();
    }

    // cross-wave reduction: reuse tile LDS as part[4][64][20]
    float* pp = &tile[0][0][0];
#pragma unroll
    for (int c = 0; c < 20; c++) pp[wv * 1280 + lane * 20 + c] = acc[c];
    __syncthreads();
#pragma unroll
    for (int j = 0; j < 5; ++j) {
        int idx = threadIdx.x * 5 + j;            // 0..1279
        int row = idx / 20, c = idx - row * 20;
        if (rowbase + row < VOCAB) {
            float s = pp[idx] + pp[1280 + idx] + pp[2560 + idx] + pp[3840 + idx];
            hv[(long)(rowbase + row) * 20 + c] = s;
        }
    }
}

// ---------------- kernel 2a: response graphs -> resp_gcn[B][50][10], u_cross[B][50][10] ----------------
__global__ __launch_bounds__(64) void k_resp(const int* __restrict__ rtok,  // [B][50]
                                             const float* __restrict__ hv,  // [VOCAB][20]
                                             const int* __restrict__ adj,   // [B][2][128]
                                             const float* __restrict__ conv_b,
                                             const float* __restrict__ att, // [50][50]
                                             float* __restrict__ gcn_out,
                                             float* __restrict__ cross_out) {
    __shared__ float hs[SS][20];
    __shared__ int esrc[EE], edst[EE];
    __shared__ float enorm[EE];
    __shared__ int degi[SS];
    __shared__ float dinv[SS];
    const int b = blockIdx.x, lane = threadIdx.x;
    const int* tb = rtok + (long)b * SS;
    for (int i = lane; i < SS * 20; i += 64) {
        int s = i / 20;
        ((float*)hs)[i] = hv[(long)tb[s] * 20 + (i - s * 20)];
    }
    const int* ab = adj + (long)b * 2 * EE;
    if (lane < SS) degi[lane] = 1;  // self loop
    for (int e = lane; e < EE; e += 64) { esrc[e] = ab[e]; edst[e] = ab[EE + e]; }
    __syncthreads();
    for (int e = lane; e < EE; e += 64) atomicAdd(&degi[edst[e]], 1);
    __syncthreads();
    if (lane < SS) dinv[lane] = 1.0f / sqrtf(fmaxf((float)degi[lane], 1e-12f));
    __syncthreads();
    for (int e = lane; e < EE; e += 64) enorm[e] = dinv[esrc[e]] * dinv[edst[e]];
    __syncthreads();

    const int p = lane;
    if (p < SS) {
        float acc[CC];
        float dp2 = dinv[p] * dinv[p];
#pragma unroll
        for (int c = 0; c < CC; c++) acc[c] = hs[p][c] * dp2 + conv_b[c];
        for (int e = 0; e < EE; e++) {
            if (edst[e] == p) {
                float nm = enorm[e];
                int s = esrc[e];
#pragma unroll
                for (int c = 0; c < CC; c++) acc[c] = fmaf(hs[s][c], nm, acc[c]);
            }
        }
        float* go = gcn_out + ((long)b * SS + p) * CC;
#pragma unroll
        for (int c = 0; c < CC; c++) go[c] = acc[c];
        float ax[CC];
#pragma unroll
        for (int c = 0; c < CC; c++) ax[c] = 0.f;
        for (int s = 0; s < SS; s++) {
            float a = att[p * SS + s];
#pragma unroll
            for (int c = 0; c < CC; c++) ax[c] = fmaf(a, hs[s][10 + c], ax[c]);
        }
        float* xo = cross_out + ((long)b * SS + p) * CC;
#pragma unroll
        for (int c = 0; c < CC; c++) xo[c] = ax[c];
    }
}

// ---------------- kernel 2b: utterance graphs + both mpm calls -> g_u, g_r [B*T][20] ----------------
__global__ __launch_bounds__(64) void k_utt(const int* __restrict__ ctok,  // [B*T][50]
                                            const float* __restrict__ hv,  // [VOCAB][20]
                                            const int* __restrict__ adj,   // [B*T][2][128]
                                            const float* __restrict__ conv_b,
                                            const float* __restrict__ att,
                                            const float* __restrict__ assign,  // [50][10]
                                            const float* __restrict__ W1, const float* __restrict__ b1,
                                            const float* __restrict__ W2, const float* __restrict__ b2,
                                            const float* __restrict__ resp_gcn, // [B][50][10]
                                            const float* __restrict__ u_cross,  // [B][50][10]
                                            float* __restrict__ g_u,
                                            float* __restrict__ g_r) {
    __shared__ float hs[SS][20];
    __shared__ int esrc[EE], edst[EE];
    __shared__ float enorm[EE];
    __shared__ int degi[SS];
    __shared__ float dinv[SS];
    __shared__ float sg[SS][CC];   // ctx gcn
    __shared__ float xr[SS][CC];   // r_cross
    __shared__ float sr[SS][CC];   // resp gcn
    __shared__ float xu[SS][CC];   // u_cross
    __shared__ float asg[SS][CC];  // assign
    const int g = blockIdx.x;
    const int b = g / TT;
    const int lane = threadIdx.x;

    const int* tb = ctok + (long)g * SS;
    for (int i = lane; i < SS * 20; i += 64) {
        int s = i / 20;
        ((float*)hs)[i] = hv[(long)tb[s] * 20 + (i - s * 20)];
    }
    const int* ab = adj + (long)g * 2 * EE;
    if (lane < SS) degi[lane] = 1;
    for (int e = lane; e < EE; e += 64) { esrc[e] = ab[e]; edst[e] = ab[EE + e]; }
    for (int i = lane; i < SS * CC; i += 64) {
        ((float*)sr)[i] = resp_gcn[(long)b * SS * CC + i];
        ((float*)xu)[i] = u_cross[(long)b * SS * CC + i];
        ((float*)asg)[i] = assign[i];
    }
    __syncthreads();
    for (int e = lane; e < EE; e += 64) atomicAdd(&degi[edst[e]], 1);
    __syncthreads();
    if (lane < SS) dinv[lane] = 1.0f / sqrtf(fmaxf((float)degi[lane], 1e-12f));
    __syncthreads();
    for (int e = lane; e < EE; e += 64) enorm[e] = dinv[esrc[e]] * dinv[edst[e]];
    __syncthreads();

    const int p = lane;
    if (p < SS) {
        float acc[CC];
        float dp2 = dinv[p] * dinv[p];
#pragma unroll
        for (int c = 0; c < CC; c++) acc[c] = hs[p][c] * dp2 + conv_b[c];
        for (int e = 0; e < EE; e++) {
            if (edst[e] == p) {
                float nm = enorm[e];
                int s = esrc[e];
#pragma unroll
                for (int c = 0; c < CC; c++) acc[c] = fmaf(hs[s][c], nm, acc[c]);
            }
        }
#pragma unroll
        for (int c = 0; c < CC; c++) sg[p][c] = acc[c];
        float ax[CC];
#pragma unroll
        for (int c = 0; c < CC; c++) ax[c] = 0.f;
        for (int s = 0; s < SS; s++) {
            float a = att[p * SS + s];
#pragma unroll
            for (int c = 0; c < CC; c++) ax[c] = fmaf(a, hs[s][10 + c], ax[c]);
        }
#pragma unroll
        for (int c = 0; c < CC; c++) xr[p][c] = ax[c];
    }
    __syncthreads();

    for (int which = 0; which < 2; ++which) {
        const float(*sf)[CC] = which ? sr : sg;
        const float(*cf)[CC] = which ? xr : xu;
        float h2[20];
        if (lane < SS) {
            const int s = lane;
            float num = 0.f, na = 0.f, nc2 = 0.f;
#pragma unroll
            for (int c = 0; c < CC; c++) {
                float av = asg[s][c];
                float a = av * sf[s][c];
                float cx = av * cf[s][c];
                num = fmaf(a, cx, num);
                na = fmaf(a, a, na);
                nc2 = fmaf(cx, cx, nc2);
            }
            float cosv = num / fmaxf(sqrtf(na) * sqrtf(nc2), 1e-8f);
            float h1[20];
#pragma unroll
            for (int j = 0; j < 20; j++) h1[j] = fmaf(cosv, W1[j], b1[j]);
#pragma unroll
            for (int k = 0; k < CC; k++) {
                float sv = sf[s][k];
#pragma unroll
                for (int j = 0; j < 20; j++) h1[j] = fmaf(sv, W1[(k + 1) * 20 + j], h1[j]);
            }
#pragma unroll
            for (int j = 0; j < 20; j++) h1[j] = fmaxf(h1[j], 0.f);
#pragma unroll
            for (int j = 0; j < 20; j++) {
                float t = b2[j];
#pragma unroll
                for (int k = 0; k < 20; k++) t = fmaf(h1[k], W2[k * 20 + j], t);
                h2[j] = t;
            }
        } else {
#pragma unroll
            for (int j = 0; j < 20; j++) h2[j] = -1e30f;
        }
        for (int off = 32; off; off >>= 1) {
#pragma unroll
            for (int j = 0; j < 20; j++) h2[j] = fmaxf(h2[j], __shfl_xor(h2[j], off));
        }
        if (lane == 0) {
            float* o = (which ? g_r : g_u) + (long)g * 20;
#pragma unroll
            for (int j = 0; j < 20; j++) o[j] = h2[j];
        }
    }
}

// ---------------- kernel 3: final FFN + sum over T + sigmoid ----------------
__global__ __launch_bounds__(64) void k_final(const float* __restrict__ g_u, const float* __restrict__ g_r,
                                              const float* __restrict__ W1, const float* __restrict__ b1,
                                              const float* __restrict__ W2, const float* __restrict__ b2,
                                              float* __restrict__ out) {
    const int b = blockIdx.x, lane = threadIdx.x;
    float ssum = 0.f;
    for (int t = 0; t < TT; t++) {
        const float* gu = g_u + ((long)b * TT + t) * 20;
        const float* gr = g_r + ((long)b * TT + t) * 20;
        float feat[80];
#pragma unroll
        for (int k = 0; k < 20; k++) {
            float u = gu[k], r = gr[k];
            feat[k] = u;
            feat[20 + k] = r;
            feat[40 + k] = u * r;
            feat[60 + k] = fabsf(u - r);
        }
        if (lane < 40) {
            float hv = b1[lane];
#pragma unroll
            for (int k = 0; k < 80; k++) hv = fmaf(feat[k], W1[k * 40 + lane], hv);
            ssum += fmaxf(hv, 0.f) * W2[lane];
        }
    }
    for (int off = 32; off; off >>= 1) ssum += __shfl_xor(ssum, off);
    if (lane == 0) out[b] = 1.f / (1.f + expf(-(ssum + (float)TT * b2[0])));
}

extern "C" void kernel_launch(void* const* d_in, const int* in_sizes, int n_in,
                              void* d_out, int out_size, void* d_ws, size_t ws_size,
                              hipStream_t stream) {
    (void)in_sizes; (void)n_in; (void)out_size; (void)ws_size;
    const int* ctx_tok = (const int*)d_in[0];
    const int* resp_tok = (const int*)d_in[1];
    const int* ctx_adj = (const int*)d_in[2];
    const int* resp_adj = (const int*)d_in[3];
    const float* emb = (const float*)d_in[4];
    const float* convW = (const float*)d_in[5];
    const float* convb = (const float*)d_in[6];
    const float* crossW = (const float*)d_in[7];
    const float* att = (const float*)d_in[8];
    const float* assign = (const float*)d_in[9];
    const float* mpW1 = (const float*)d_in[10];
    const float* mpb1 = (const float*)d_in[11];
    const float* mpW2 = (const float*)d_in[12];
    const float* mpb2 = (const float*)d_in[13];
    const float* fW1 = (const float*)d_in[14];
    const float* fb1 = (const float*)d_in[15];
    const float* fW2 = (const float*)d_in[16];
    const float* fb2 = (const float*)d_in[17];

    float* ws = (float*)d_ws;
    float* Wall = ws;                       // 15,360
    float* hvocab = Wall + 15360;           // 422,560   [VOCAB][20]
    float* rgcn = hvocab + 422560;          // 256,000   [B][50][10]
    float* ucx = rgcn + 256000;             // 256,000   [B][50][10]
    float* gu = ucx + 256000;               // 51,200    [B*T][20]
    float* gr = gu + 51200;                 // 51,200
    float* outf = (float*)d_out;

    hipLaunchKernelGGL(k_fusew, dim3(60), dim3(256), 0, stream, convW, crossW, Wall);
    hipLaunchKernelGGL(k_vocab, dim3((VOCAB + 63) / 64), dim3(256), 0, stream, emb, Wall, hvocab);
    hipLaunchKernelGGL(k_resp, dim3(BB), dim3(64), 0, stream, resp_tok, hvocab, resp_adj, convb, att, rgcn, ucx);
    hipLaunchKernelGGL(k_utt, dim3(BB * TT), dim3(64), 0, stream, ctx_tok, hvocab, ctx_adj, convb, att, assign,
                       mpW1, mpb1, mpW2, mpb2, rgcn, ucx, gu, gr);
    hipLaunchKernelGGL(k_final, dim3(BB), dim3(64), 0, stream, gu, gr, fW1, fb1, fW2, fb2, outf);
}

// Round 3
// 139.772 us; speedup vs baseline: 2.0027x; 1.3005x over previous
//
#include <hip/hip_runtime.h>
#include <math.h>

#define VOCAB 21128
#define DD 768
#define SS 50
#define TT 5
#define BB 512
#define EE 128
#define CC 10

// ---------------- kernel 1: hvocab[21128][20] = emb @ [convW | crossW] ----------------
// 331 blocks x 512 threads (8 waves). Wave wv owns d-range [wv*96, wv*96+96) for the
// block's 64 rows, in 3 chunks of 32 d. lane = row; staging coalesced (8 lanes x float4
// cover 32 d of one row); W via wave-uniform scalar loads; deterministic LDS reduce.
__global__ __launch_bounds__(512) void k_vocab(const float* __restrict__ emb,
                                               const float* __restrict__ Wconv,
                                               const float* __restrict__ Wcross,
                                               float* __restrict__ hv) {
    __shared__ float tile[8][64][33];  // 67.6 KB -> 2 blocks/CU
    const int wv = threadIdx.x >> 6, lane = threadIdx.x & 63;
    const int rowbase = blockIdx.x * 64;
    const int g8 = lane >> 3, m = lane & 7;

    float acc[20];
#pragma unroll
    for (int c = 0; c < 20; c++) acc[c] = 0.f;

    for (int chunk = 0; chunk < 3; ++chunk) {
        const int d0 = wv * 96 + chunk * 32;
        __syncthreads();  // previous chunk's reads done before overwrite
#pragma unroll
        for (int it = 0; it < 8; ++it) {
            int row = it * 8 + g8;
            long r = rowbase + row;
            if (r >= VOCAB) r = VOCAB - 1;
            const float4 v = *(const float4*)(emb + r * DD + d0 + m * 4);
            tile[wv][row][m * 4 + 0] = v.x;
            tile[wv][row][m * 4 + 1] = v.y;
            tile[wv][row][m * 4 + 2] = v.z;
            tile[wv][row][m * 4 + 3] = v.w;
        }
        __syncthreads();
#pragma unroll 4
        for (int d = 0; d < 32; ++d) {
            float e = tile[wv][lane][d];
            const float* wc = Wconv + (d0 + d) * 10;   // wave-uniform -> scalar loads
            const float* wx = Wcross + (d0 + d) * 10;
#pragma unroll
            for (int c = 0; c < 10; c++) {
                acc[c] = fmaf(e, wc[c], acc[c]);
                acc[10 + c] = fmaf(e, wx[c], acc[10 + c]);
            }
        }
    }

    __syncthreads();
    float* pp = &tile[0][0][0];  // reuse as part[8][64][20]
#pragma unroll
    for (int c = 0; c < 20; c++) pp[wv * 1280 + lane * 20 + c] = acc[c];
    __syncthreads();
    for (int i = threadIdx.x; i < 1280; i += 512) {
        int row = i / 20;
        long r = rowbase + row;
        if (r < VOCAB) {
            float s = 0.f;
#pragma unroll
            for (int w = 0; w < 8; ++w) s += pp[w * 1280 + i];
            hv[r * 20 + (i - row * 20)] = s;
        }
    }
}

// ---------------- kernel 2: whole batch fused ----------------
// grid = B, 384 threads = 6 waves. Waves 0-4: utterance graphs; wave 5: response graph.
// Per wave: gather hs, deterministic edge counting-sort, GCN, cross-attention; then
// mpm (waves 0-4, self/cross register-resident where possible), final FFN + sigmoid.
__global__ __launch_bounds__(384) void k_batch(const int* __restrict__ ctok,   // [B][T][50]
                                               const int* __restrict__ rtok,   // [B][50]
                                               const int* __restrict__ cadj,   // [B][T][2][128]
                                               const int* __restrict__ radj,   // [B][2][128]
                                               const float* __restrict__ hv,   // [VOCAB][20]
                                               const float* __restrict__ convb,
                                               const float* __restrict__ att,  // [50][50]
                                               const float* __restrict__ assign, // [50][10]
                                               const float* __restrict__ W1, const float* __restrict__ b1,
                                               const float* __restrict__ W2, const float* __restrict__ b2,
                                               const float* __restrict__ fW1, const float* __restrict__ fb1,
                                               const float* __restrict__ fW2, const float* __restrict__ fb2,
                                               float* __restrict__ out) {
    __shared__ float attL[SS][51];
    __shared__ float asgL[SS][11];
    __shared__ float srS[SS][11];   // resp gcn
    __shared__ float xuS[SS][11];   // u_cross
    __shared__ float guS[TT][20];
    __shared__ float grS[TT][20];
    __shared__ float fsum[256];
    __shared__ float hsA[6][SS][21];
    __shared__ int tksA[6][SS];
    __shared__ int esA[6][EE];
    __shared__ int edA[6][EE];
    __shared__ int ssA[6][EE];
    __shared__ float snA[6][EE];
    __shared__ int dgA[6][SS];
    __shared__ float dvA[6][SS];
    __shared__ int ofA[6][SS];

    const int b = blockIdx.x;
    const int tid = threadIdx.x;
    const int wv = tid >> 6, lane = tid & 63;
    const bool isResp = (wv == 5);

    // ---- P0: stage shared + per-graph raw data ----
    for (int i = tid; i < SS * SS; i += 384) attL[i / SS][i % SS] = att[i];
    for (int i = tid; i < SS * CC; i += 384) asgL[i / CC][i % CC] = assign[i];
    const int* tb = isResp ? (rtok + (long)b * SS) : (ctok + ((long)b * TT + wv) * SS);
    const int* ab = isResp ? (radj + (long)b * 2 * EE) : (cadj + ((long)b * TT + wv) * 2 * EE);
    if (lane < SS) { tksA[wv][lane] = tb[lane]; dgA[wv][lane] = 1; }
    esA[wv][lane] = ab[lane];
    esA[wv][lane + 64] = ab[lane + 64];
    edA[wv][lane] = ab[EE + lane];
    edA[wv][lane + 64] = ab[EE + lane + 64];
    __syncthreads();

    // ---- P1: hs gather + degree count ----
    for (int i = lane; i < SS * 20; i += 64) {
        int s = i / 20, c = i - s * 20;
        hsA[wv][s][c] = hv[(long)tksA[wv][s] * 20 + c];
    }
    atomicAdd(&dgA[wv][edA[wv][lane]], 1);
    atomicAdd(&dgA[wv][edA[wv][lane + 64]], 1);
    __syncthreads();

    // ---- P2: dinv + exclusive prefix of edge counts ----
    if (lane < SS) dvA[wv][lane] = rsqrtf((float)dgA[wv][lane]);
    int cnt = (lane < SS) ? (dgA[wv][lane] - 1) : 0;
    int incl = cnt;
#pragma unroll
    for (int o = 1; o < 64; o <<= 1) {
        int v = __shfl_up(incl, o);
        if (lane >= o) incl += v;
    }
    if (lane < SS) ofA[wv][lane] = incl - cnt;
    __syncthreads();

    // ---- P3: stable rank (edge-index order) + scatter into per-dst lists ----
    {
        const int e1 = lane, e2 = lane + 64;
        const int d1 = edA[wv][e1], d2 = edA[wv][e2];
        int r1 = 0, r2 = 0;
        for (int k = 0; k < EE - 1; ++k) {   // uniform k -> broadcast LDS read
            int dk = edA[wv][k];
            r1 += (int)((k < e1) & (dk == d1));
            r2 += (int)((k < e2) & (dk == d2));
        }
        int s1 = esA[wv][e1], s2 = esA[wv][e2];
        int p1 = ofA[wv][d1] + r1, p2 = ofA[wv][d2] + r2;
        ssA[wv][p1] = s1; snA[wv][p1] = dvA[wv][s1] * dvA[wv][d1];
        ssA[wv][p2] = s2; snA[wv][p2] = dvA[wv][s2] * dvA[wv][d2];
    }
    __syncthreads();

    // ---- P4: GCN aggregate + cross attention ----
    float sg[CC], xr[CC];
#pragma unroll
    for (int c = 0; c < CC; c++) { sg[c] = 0.f; xr[c] = 0.f; }
    const int p = lane;
    if (p < SS) {
        float acc[CC];
        float dp2 = dvA[wv][p] * dvA[wv][p];
#pragma unroll
        for (int c = 0; c < CC; c++) acc[c] = hsA[wv][p][c] * dp2 + convb[c];
        const int base = ofA[wv][p], n = dgA[wv][p] - 1;
        for (int j = 0; j < n; ++j) {
            int s = ssA[wv][base + j];
            float nm = snA[wv][base + j];
#pragma unroll
            for (int c = 0; c < CC; c++) acc[c] = fmaf(hsA[wv][s][c], nm, acc[c]);
        }
        float ax[CC];
#pragma unroll
        for (int c = 0; c < CC; c++) ax[c] = 0.f;
        for (int s = 0; s < SS; ++s) {
            float a = attL[p][s];
#pragma unroll
            for (int c = 0; c < CC; c++) ax[c] = fmaf(a, hsA[wv][s][10 + c], ax[c]);
        }
        if (isResp) {
#pragma unroll
            for (int c = 0; c < CC; c++) { srS[p][c] = acc[c]; xuS[p][c] = ax[c]; }
        } else {
#pragma unroll
            for (int c = 0; c < CC; c++) { sg[c] = acc[c]; xr[c] = ax[c]; }
        }
    }
    __syncthreads();

    // ---- P5: mpm x2 for utterance waves ----
    if (!isResp) {
#pragma unroll
        for (int which = 0; which < 2; ++which) {
            float h2[20];
            if (lane < SS) {
                float self[CC], cro[CC];
#pragma unroll
                for (int c = 0; c < CC; c++) {
                    self[c] = which ? srS[lane][c] : sg[c];
                    cro[c] = which ? xr[c] : xuS[lane][c];
                }
                float num = 0.f, na = 0.f, nc2 = 0.f;
#pragma unroll
                for (int c = 0; c < CC; c++) {
                    float av = asgL[lane][c];
                    float a = av * self[c];
                    float cx = av * cro[c];
                    num = fmaf(a, cx, num);
                    na = fmaf(a, a, na);
                    nc2 = fmaf(cx, cx, nc2);
                }
                float cosv = num / fmaxf(sqrtf(na) * sqrtf(nc2), 1e-8f);
                float h1[20];
#pragma unroll
                for (int j = 0; j < 20; j++) h1[j] = fmaf(cosv, W1[j], b1[j]);
#pragma unroll
                for (int k = 0; k < CC; k++) {
                    float sv = self[k];
#pragma unroll
                    for (int j = 0; j < 20; j++) h1[j] = fmaf(sv, W1[(k + 1) * 20 + j], h1[j]);
                }
#pragma unroll
                for (int j = 0; j < 20; j++) h1[j] = fmaxf(h1[j], 0.f);
#pragma unroll
                for (int j = 0; j < 20; j++) {
                    float t = b2[j];
#pragma unroll
                    for (int k = 0; k < 20; k++) t = fmaf(h1[k], W2[k * 20 + j], t);
                    h2[j] = t;
                }
            } else {
#pragma unroll
                for (int j = 0; j < 20; j++) h2[j] = -1e30f;
            }
#pragma unroll
            for (int o = 32; o; o >>= 1) {
#pragma unroll
                for (int j = 0; j < 20; j++) h2[j] = fmaxf(h2[j], __shfl_xor(h2[j], o));
            }
            if (lane == 0) {
                float* o = which ? grS[wv] : guS[wv];
#pragma unroll
                for (int j = 0; j < 20; j++) o[j] = h2[j];
            }
        }
    }
    __syncthreads();

    // ---- P6: final FFN + reduce + sigmoid ----
    float term = 0.f;
    if (tid < 200) {
        const int t = tid / 40, j = tid - t * 40;
        float hvv = fb1[j];
#pragma unroll
        for (int k = 0; k < 20; k++) {
            float u = guS[t][k], r = grS[t][k];
            hvv = fmaf(u, fW1[k * 40 + j], hvv);
            hvv = fmaf(r, fW1[(20 + k) * 40 + j], hvv);
            hvv = fmaf(u * r, fW1[(40 + k) * 40 + j], hvv);
            hvv = fmaf(fabsf(u - r), fW1[(60 + k) * 40 + j], hvv);
        }
        term = fmaxf(hvv, 0.f) * fW2[j];
    }
    if (tid < 256) fsum[tid] = term;
    __syncthreads();
    if (wv == 0) {
        float s = fsum[lane] + fsum[lane + 64] + fsum[lane + 128] + fsum[lane + 192];
#pragma unroll
        for (int o = 32; o; o >>= 1) s += __shfl_xor(s, o);
        if (lane == 0) out[b] = 1.f / (1.f + expf(-(s + (float)TT * fb2[0])));
    }
}

extern "C" void kernel_launch(void* const* d_in, const int* in_sizes, int n_in,
                              void* d_out, int out_size, void* d_ws, size_t ws_size,
                              hipStream_t stream) {
    (void)in_sizes; (void)n_in; (void)out_size; (void)ws_size;
    const int* ctx_tok = (const int*)d_in[0];
    const int* resp_tok = (const int*)d_in[1];
    const int* ctx_adj = (const int*)d_in[2];
    const int* resp_adj = (const int*)d_in[3];
    const float* emb = (const float*)d_in[4];
    const float* convW = (const float*)d_in[5];
    const float* convb = (const float*)d_in[6];
    const float* crossW = (const float*)d_in[7];
    const float* att = (const float*)d_in[8];
    const float* assign = (const float*)d_in[9];
    const float* mpW1 = (const float*)d_in[10];
    const float* mpb1 = (const float*)d_in[11];
    const float* mpW2 = (const float*)d_in[12];
    const float* mpb2 = (const float*)d_in[13];
    const float* fW1 = (const float*)d_in[14];
    const float* fb1 = (const float*)d_in[15];
    const float* fW2 = (const float*)d_in[16];
    const float* fb2 = (const float*)d_in[17];

    float* hvocab = (float*)d_ws;  // [VOCAB][20] = 1.69 MB
    float* outf = (float*)d_out;

    hipLaunchKernelGGL(k_vocab, dim3((VOCAB + 63) / 64), dim3(512), 0, stream,
                       emb, convW, crossW, hvocab);
    hipLaunchKernelGGL(k_batch, dim3(BB), dim3(384), 0, stream,
                       ctx_tok, resp_tok, ctx_adj, resp_adj, hvocab, convb, att, assign,
                       mpW1, mpb1, mpW2, mpb2, fW1, fb1, fW2, fb2, outf);
}

// Round 4
// 91.722 us; speedup vs baseline: 3.0518x; 1.5239x over previous
//
#include <hip/hip_runtime.h>
#include <math.h>

#define VOCAB 21128
#define DD 768
#define SS 50
#define TT 5
#define BB 512
#define EE 128
#define CC 10

// ---------------- kernel 1: hvocab[21128][20] = emb @ [convW | crossW] ----------------
// 331 blocks x 512 threads (8 waves). Wave wv owns d-range [wv*96, wv*96+96) for the
// block's 64 rows, 3 chunks of 32 d. lane = row. KEY: d0 forced into an SGPR via
// readfirstlane so W loads are s_loads (round-3 version emitted per-lane vector loads
// -> VALUBusy 7%). tile[wv] is wave-private -> NO barriers in the chunk loop.
__global__ __launch_bounds__(512) void k_vocab(const float* __restrict__ emb,
                                               const float* __restrict__ Wconv,
                                               const float* __restrict__ Wcross,
                                               float* __restrict__ hv) {
    __shared__ float tile[8][64][33];  // 67.6 KB -> 2 blocks/CU
    const int wv = threadIdx.x >> 6, lane = threadIdx.x & 63;
    const int rowbase = blockIdx.x * 64;
    const int g8 = lane >> 3, m = lane & 7;

    float acc[20];
#pragma unroll
    for (int c = 0; c < 20; c++) acc[c] = 0.f;

    const int d0w = __builtin_amdgcn_readfirstlane(wv * 96);  // SGPR: W loads -> s_load

    for (int chunk = 0; chunk < 3; ++chunk) {
        const int d0 = d0w + chunk * 32;  // scalar
        // stage 64 rows x 32 d, coalesced: 8 lanes x float4 = 128B contiguous per row
#pragma unroll
        for (int it = 0; it < 8; ++it) {
            int row = it * 8 + g8;
            long r = rowbase + row;
            if (r >= VOCAB) r = VOCAB - 1;
            const float4 v = *(const float4*)(emb + r * DD + d0 + m * 4);
            tile[wv][row][m * 4 + 0] = v.x;
            tile[wv][row][m * 4 + 1] = v.y;
            tile[wv][row][m * 4 + 2] = v.z;
            tile[wv][row][m * 4 + 3] = v.w;
        }
        // no __syncthreads: tile[wv] is private to this wave; compiler's lgkmcnt
        // ordering covers the intra-wave ds_write -> ds_read dependency.
#pragma unroll 8
        for (int d = 0; d < 32; ++d) {
            float e = tile[wv][lane][d];
            const float* wc = Wconv + (d0 + d) * 10;   // scalar address -> s_load
            const float* wx = Wcross + (d0 + d) * 10;
#pragma unroll
            for (int c = 0; c < 10; c++) {
                acc[c] = fmaf(e, wc[c], acc[c]);
                acc[10 + c] = fmaf(e, wx[c], acc[10 + c]);
            }
        }
    }

    __syncthreads();  // pp region below aliases other waves' tiles
    float* pp = &tile[0][0][0];  // reuse as part[8][64][20]
#pragma unroll
    for (int c = 0; c < 20; c++) pp[wv * 1280 + lane * 20 + c] = acc[c];
    __syncthreads();
    for (int i = threadIdx.x; i < 1280; i += 512) {
        int row = i / 20;
        long r = rowbase + row;
        if (r < VOCAB) {
            float s = 0.f;
#pragma unroll
            for (int w = 0; w < 8; ++w) s += pp[w * 1280 + i];
            hv[r * 20 + (i - row * 20)] = s;
        }
    }
}

// ---------------- kernel 2: whole batch fused ----------------
// grid = B, 384 threads = 6 waves. Waves 0-4: utterance graphs; wave 5: response graph.
__global__ __launch_bounds__(384) void k_batch(const int* __restrict__ ctok,   // [B][T][50]
                                               const int* __restrict__ rtok,   // [B][50]
                                               const int* __restrict__ cadj,   // [B][T][2][128]
                                               const int* __restrict__ radj,   // [B][2][128]
                                               const float* __restrict__ hv,   // [VOCAB][20]
                                               const float* __restrict__ convb,
                                               const float* __restrict__ att,  // [50][50]
                                               const float* __restrict__ assign, // [50][10]
                                               const float* __restrict__ W1, const float* __restrict__ b1,
                                               const float* __restrict__ W2, const float* __restrict__ b2,
                                               const float* __restrict__ fW1, const float* __restrict__ fb1,
                                               const float* __restrict__ fW2, const float* __restrict__ fb2,
                                               float* __restrict__ out) {
    __shared__ float attL[SS][51];
    __shared__ float asgL[SS][11];
    __shared__ float srS[SS][11];   // resp gcn
    __shared__ float xuS[SS][11];   // u_cross
    __shared__ float guS[TT][20];
    __shared__ float grS[TT][20];
    __shared__ float fsum[256];
    __shared__ float hsA[6][SS][21];
    __shared__ int tksA[6][SS];
    __shared__ int esA[6][EE];
    __shared__ int edA[6][EE];
    __shared__ int ssA[6][EE];
    __shared__ float snA[6][EE];
    __shared__ int dgA[6][SS];
    __shared__ float dvA[6][SS];
    __shared__ int ofA[6][SS];

    const int b = blockIdx.x;
    const int tid = threadIdx.x;
    const int wv = tid >> 6, lane = tid & 63;
    const bool isResp = (wv == 5);

    // ---- P0: stage shared + per-graph raw data ----
    for (int i = tid; i < SS * SS; i += 384) attL[i / SS][i % SS] = att[i];
    for (int i = tid; i < SS * CC; i += 384) asgL[i / CC][i % CC] = assign[i];
    const int* tb = isResp ? (rtok + (long)b * SS) : (ctok + ((long)b * TT + wv) * SS);
    const int* ab = isResp ? (radj + (long)b * 2 * EE) : (cadj + ((long)b * TT + wv) * 2 * EE);
    if (lane < SS) { tksA[wv][lane] = tb[lane]; dgA[wv][lane] = 1; }
    esA[wv][lane] = ab[lane];
    esA[wv][lane + 64] = ab[lane + 64];
    edA[wv][lane] = ab[EE + lane];
    edA[wv][lane + 64] = ab[EE + lane + 64];
    __syncthreads();

    // ---- P1: hs gather + degree count ----
    for (int i = lane; i < SS * 20; i += 64) {
        int s = i / 20, c = i - s * 20;
        hsA[wv][s][c] = hv[(long)tksA[wv][s] * 20 + c];
    }
    atomicAdd(&dgA[wv][edA[wv][lane]], 1);
    atomicAdd(&dgA[wv][edA[wv][lane + 64]], 1);
    __syncthreads();

    // ---- P2: dinv + exclusive prefix of edge counts ----
    if (lane < SS) dvA[wv][lane] = rsqrtf((float)dgA[wv][lane]);
    int cnt = (lane < SS) ? (dgA[wv][lane] - 1) : 0;
    int incl = cnt;
#pragma unroll
    for (int o = 1; o < 64; o <<= 1) {
        int v = __shfl_up(incl, o);
        if (lane >= o) incl += v;
    }
    if (lane < SS) ofA[wv][lane] = incl - cnt;
    __syncthreads();

    // ---- P3: stable rank (edge-index order) + scatter into per-dst lists ----
    {
        const int e1 = lane, e2 = lane + 64;
        const int d1 = edA[wv][e1], d2 = edA[wv][e2];
        int r1 = 0, r2 = 0;
#pragma unroll 8
        for (int k = 0; k < EE - 1; ++k) {   // uniform k -> broadcast LDS read
            int dk = edA[wv][k];
            r1 += (int)((k < e1) & (dk == d1));
            r2 += (int)((k < e2) & (dk == d2));
        }
        int s1 = esA[wv][e1], s2 = esA[wv][e2];
        int p1 = ofA[wv][d1] + r1, p2 = ofA[wv][d2] + r2;
        ssA[wv][p1] = s1; snA[wv][p1] = dvA[wv][s1] * dvA[wv][d1];
        ssA[wv][p2] = s2; snA[wv][p2] = dvA[wv][s2] * dvA[wv][d2];
    }
    __syncthreads();

    // ---- P4: GCN aggregate + cross attention ----
    float sg[CC], xr[CC];
#pragma unroll
    for (int c = 0; c < CC; c++) { sg[c] = 0.f; xr[c] = 0.f; }
    const int p = lane;
    if (p < SS) {
        float acc[CC];
        float dp2 = dvA[wv][p] * dvA[wv][p];
#pragma unroll
        for (int c = 0; c < CC; c++) acc[c] = hsA[wv][p][c] * dp2 + convb[c];
        const int base = ofA[wv][p], n = dgA[wv][p] - 1;
        for (int j = 0; j < n; ++j) {
            int s = ssA[wv][base + j];
            float nm = snA[wv][base + j];
#pragma unroll
            for (int c = 0; c < CC; c++) acc[c] = fmaf(hsA[wv][s][c], nm, acc[c]);
        }
        float ax[CC];
#pragma unroll
        for (int c = 0; c < CC; c++) ax[c] = 0.f;
        for (int s = 0; s < SS; ++s) {
            float a = attL[p][s];
#pragma unroll
            for (int c = 0; c < CC; c++) ax[c] = fmaf(a, hsA[wv][s][10 + c], ax[c]);
        }
        if (isResp) {
#pragma unroll
            for (int c = 0; c < CC; c++) { srS[p][c] = acc[c]; xuS[p][c] = ax[c]; }
        } else {
#pragma unroll
            for (int c = 0; c < CC; c++) { sg[c] = acc[c]; xr[c] = ax[c]; }
        }
    }
    __syncthreads();

    // ---- P5: mpm x2 for utterance waves ----
    if (!isResp) {
#pragma unroll
        for (int which = 0; which < 2; ++which) {
            float h2[20];
            if (lane < SS) {
                float self[CC], cro[CC];
#pragma unroll
                for (int c = 0; c < CC; c++) {
                    self[c] = which ? srS[lane][c] : sg[c];
                    cro[c] = which ? xr[c] : xuS[lane][c];
                }
                float num = 0.f, na = 0.f, nc2 = 0.f;
#pragma unroll
                for (int c = 0; c < CC; c++) {
                    float av = asgL[lane][c];
                    float a = av * self[c];
                    float cx = av * cro[c];
                    num = fmaf(a, cx, num);
                    na = fmaf(a, a, na);
                    nc2 = fmaf(cx, cx, nc2);
                }
                float cosv = num / fmaxf(sqrtf(na) * sqrtf(nc2), 1e-8f);
                float h1[20];
#pragma unroll
                for (int j = 0; j < 20; j++) h1[j] = fmaf(cosv, W1[j], b1[j]);
#pragma unroll
                for (int k = 0; k < CC; k++) {
                    float sv = self[k];
#pragma unroll
                    for (int j = 0; j < 20; j++) h1[j] = fmaf(sv, W1[(k + 1) * 20 + j], h1[j]);
                }
#pragma unroll
                for (int j = 0; j < 20; j++) h1[j] = fmaxf(h1[j], 0.f);
#pragma unroll
                for (int j = 0; j < 20; j++) {
                    float t = b2[j];
#pragma unroll
                    for (int k = 0; k < 20; k++) t = fmaf(h1[k], W2[k * 20 + j], t);
                    h2[j] = t;
                }
            } else {
#pragma unroll
                for (int j = 0; j < 20; j++) h2[j] = -1e30f;
            }
#pragma unroll
            for (int o = 32; o; o >>= 1) {
#pragma unroll
                for (int j = 0; j < 20; j++) h2[j] = fmaxf(h2[j], __shfl_xor(h2[j], o));
            }
            if (lane == 0) {
                float* o = which ? grS[wv] : guS[wv];
#pragma unroll
                for (int j = 0; j < 20; j++) o[j] = h2[j];
            }
        }
    }
    __syncthreads();

    // ---- P6: final FFN + reduce + sigmoid ----
    float term = 0.f;
    if (tid < 200) {
        const int t = tid / 40, j = tid - t * 40;
        float hvv = fb1[j];
#pragma unroll
        for (int k = 0; k < 20; k++) {
            float u = guS[t][k], r = grS[t][k];
            hvv = fmaf(u, fW1[k * 40 + j], hvv);
            hvv = fmaf(r, fW1[(20 + k) * 40 + j], hvv);
            hvv = fmaf(u * r, fW1[(40 + k) * 40 + j], hvv);
            hvv = fmaf(fabsf(u - r), fW1[(60 + k) * 40 + j], hvv);
        }
        term = fmaxf(hvv, 0.f) * fW2[j];
    }
    if (tid < 256) fsum[tid] = term;
    __syncthreads();
    if (wv == 0) {
        float s = fsum[lane] + fsum[lane + 64] + fsum[lane + 128] + fsum[lane + 192];
#pragma unroll
        for (int o = 32; o; o >>= 1) s += __shfl_xor(s, o);
        if (lane == 0) out[b] = 1.f / (1.f + expf(-(s + (float)TT * fb2[0])));
    }
}

extern "C" void kernel_launch(void* const* d_in, const int* in_sizes, int n_in,
                              void* d_out, int out_size, void* d_ws, size_t ws_size,
                              hipStream_t stream) {
    (void)in_sizes; (void)n_in; (void)out_size; (void)ws_size;
    const int* ctx_tok = (const int*)d_in[0];
    const int* resp_tok = (const int*)d_in[1];
    const int* ctx_adj = (const int*)d_in[2];
    const int* resp_adj = (const int*)d_in[3];
    const float* emb = (const float*)d_in[4];
    const float* convW = (const float*)d_in[5];
    const float* convb = (const float*)d_in[6];
    const float* crossW = (const float*)d_in[7];
    const float* att = (const float*)d_in[8];
    const float* assign = (const float*)d_in[9];
    const float* mpW1 = (const float*)d_in[10];
    const float* mpb1 = (const float*)d_in[11];
    const float* mpW2 = (const float*)d_in[12];
    const float* mpb2 = (const float*)d_in[13];
    const float* fW1 = (const float*)d_in[14];
    const float* fb1 = (const float*)d_in[15];
    const float* fW2 = (const float*)d_in[16];
    const float* fb2 = (const float*)d_in[17];

    float* hvocab = (float*)d_ws;  // [VOCAB][20] = 1.69 MB
    float* outf = (float*)d_out;

    hipLaunchKernelGGL(k_vocab, dim3((VOCAB + 63) / 64), dim3(512), 0, stream,
                       emb, convW, crossW, hvocab);
    hipLaunchKernelGGL(k_batch, dim3(BB), dim3(384), 0, stream,
                       ctx_tok, resp_tok, ctx_adj, resp_adj, hvocab, convb, att, assign,
                       mpW1, mpb1, mpW2, mpb2, fW1, fb1, fW2, fb2, outf);
}

// Round 7
// 91.614 us; speedup vs baseline: 3.0554x; 1.0012x over previous
//
#include <hip/hip_runtime.h>
#include <math.h>

#define VOCAB 21128
#define DD 768
#define SS 50
#define TT 5
#define BB 512
#define EE 128
#define CC 10
#define V20 (VOCAB * 20)

// ---------------- kernel 1: hvp[kh][21128][20] = emb[:, kh-half] @ W-half ----------------
// grid (331, 2): blockIdx.y picks a 384-wide K-half -> 662 blocks for ~2x residency.
// 8 waves x 48 d each, 3 chunks of 16 d. lane = row; W via wave-uniform scalar loads
// (d0 scalar via readfirstlane); tile[wv] wave-private -> no barriers in chunk loop.
// k_batch sums the two K-half partials during its gather.
__global__ __launch_bounds__(512) void k_vocab(const float* __restrict__ emb,
                                               const float* __restrict__ Wconv,
                                               const float* __restrict__ Wcross,
                                               float* __restrict__ hvp) {
    __shared__ float tile[8][64][21];  // 43008 B
    const int wv = threadIdx.x >> 6, lane = threadIdx.x & 63;
    const int rowbase = blockIdx.x * 64;
    const int rsub = lane >> 2, m = lane & 3;

    float acc[20];
#pragma unroll
    for (int c = 0; c < 20; c++) acc[c] = 0.f;

    const int d0w = blockIdx.y * 384 + __builtin_amdgcn_readfirstlane(wv * 48);

    for (int chunk = 0; chunk < 3; ++chunk) {
        const int d0 = d0w + chunk * 16;  // scalar
        // stage 64 rows x 16 d: 4 lanes x float4 = 64B contiguous per row
#pragma unroll
        for (int it = 0; it < 4; ++it) {
            int row = it * 16 + rsub;
            long r = rowbase + row;
            if (r >= VOCAB) r = VOCAB - 1;
            const float4 v = *(const float4*)(emb + r * DD + d0 + m * 4);
            tile[wv][row][m * 4 + 0] = v.x;
            tile[wv][row][m * 4 + 1] = v.y;
            tile[wv][row][m * 4 + 2] = v.z;
            tile[wv][row][m * 4 + 3] = v.w;
        }
#pragma unroll
        for (int d = 0; d < 16; ++d) {
            float e = tile[wv][lane][d];
            const float* wc = Wconv + (d0 + d) * 10;   // scalar address -> s_load
            const float* wx = Wcross + (d0 + d) * 10;
#pragma unroll
            for (int c = 0; c < 10; c++) {
                acc[c] = fmaf(e, wc[c], acc[c]);
                acc[10 + c] = fmaf(e, wx[c], acc[10 + c]);
            }
        }
    }

    __syncthreads();
    float* pp = &tile[0][0][0];  // reuse as part[8][64][20] (10240 <= 10752 floats)
#pragma unroll
    for (int c = 0; c < 20; c++) pp[wv * 1280 + lane * 20 + c] = acc[c];
    __syncthreads();
    float* outp = hvp + (long)blockIdx.y * V20;
    for (int i = threadIdx.x; i < 1280; i += 512) {
        int row = i / 20;
        long r = rowbase + row;
        if (r < VOCAB) {
            float s = 0.f;
#pragma unroll
            for (int w = 0; w < 8; ++w) s += pp[w * 1280 + i];
            outp[r * 20 + (i - row * 20)] = s;
        }
    }
}

// ---------------- kernel 2: whole batch fused ----------------
// grid = B (512 blocks = exactly 2/CU, grid-resident), 384 thr = 6 waves.
// Waves 0-4: utterances; wave 5: response. Edge aggregation via WAVE-PRIVATE LDS
// float atomics. KEY FIX (r5/r6 bug): the hs-gather loop had divergent trip counts
// (1000 = 15*64+40) and called __shfl inside -> last iteration read from INACTIVE
// lanes 48/49 -> token index 0 -> nodes 48/49 corrupted deterministically. Now the
// loop runs a uniform 16 iterations for all lanes; only the store is predicated.
__global__ __launch_bounds__(384) void k_batch(const int* __restrict__ ctok,   // [B][T][50]
                                               const int* __restrict__ rtok,   // [B][50]
                                               const int* __restrict__ cadj,   // [B][T][2][128]
                                               const int* __restrict__ radj,   // [B][2][128]
                                               const float* __restrict__ hvp,  // [2][VOCAB][20]
                                               const float* __restrict__ convb,
                                               const float* __restrict__ att,  // [50][50]
                                               const float* __restrict__ assign, // [50][10]
                                               const float* __restrict__ W1, const float* __restrict__ b1,
                                               const float* __restrict__ W2, const float* __restrict__ b2,
                                               const float* __restrict__ fW1, const float* __restrict__ fb1,
                                               const float* __restrict__ fW2, const float* __restrict__ fb2,
                                               float* __restrict__ out) {
    __shared__ float hsA[6][SS][21];   // 25200 B
    __shared__ float aggA[6][SS][11];  // 13200 B (float agg, then fsum reuse - float only)
    __shared__ int dgS[6][64];         // 1536 B  dedicated int degree counts
    __shared__ float attL[SS][51];     // 10200 B
    __shared__ float asgL[SS][11];     // 2200 B
    __shared__ float srS[SS][11];      // 2200 B  resp gcn
    __shared__ float xuS[SS][11];      // 2200 B  u_cross
    __shared__ float guS[TT][20];      // 400 B
    __shared__ float grS[TT][20];      // 400 B   -> total 57536 B, 2 blocks/CU

    const int b = blockIdx.x;
    const int tid = threadIdx.x;
    const int wv = tid >> 6, lane = tid & 63;
    const bool isResp = (wv == 5);
    const long gidx = (long)b * TT + wv;

    // ---- stage att/assign (block-shared) ----
    for (int i = tid; i < SS * SS; i += 384) attL[i / SS][i % SS] = att[i];
    for (int i = tid; i < SS * CC; i += 384) asgL[i / CC][i % CC] = assign[i];

    // ---- per-graph raw data -> registers (coalesced) ----
    const int* ab = isResp ? (radj + (long)b * 2 * EE) : (cadj + gidx * 2 * EE);
    const int e1s = ab[lane], e2s = ab[lane + 64];
    const int e1d = ab[EE + lane], e2d = ab[EE + lane + 64];
    const int* tb = isResp ? (rtok + (long)b * SS) : (ctok + gidx * SS);
    const int myTok = (lane < SS) ? tb[lane] : 0;

    // ---- degree count (dgS[wv] wave-private; intra-wave DS ops are in order) ----
    dgS[wv][lane] = 0;
    atomicAdd(&dgS[wv][e1d], 1);
    atomicAdd(&dgS[wv][e2d], 1);

    // ---- gather hs rows: UNIFORM trip count, shfl outside predication ----
#pragma unroll
    for (int it = 0; it < 16; ++it) {
        const int i = it * 64 + lane;
        int s = i / 20;
        const int c = i - s * 20;
        const int sc = (s < SS) ? s : (SS - 1);
        const int t = __shfl(myTok, sc);       // all 64 lanes execute: convergent
        if (i < SS * 20)
            hsA[wv][s][c] = hvp[(long)t * 20 + c] + hvp[V20 + (long)t * 20 + c];
    }

    // ---- dinv in regs ----
    float dv = 0.f;
    if (lane < SS) dv = rsqrtf((float)(dgS[wv][lane] + 1));  // +1 self loop

    // ---- zero agg, then deterministic wave-private float scatter-add ----
    float* agg = &aggA[wv][0][0];
    for (int i = lane; i < SS * 11; i += 64) agg[i] = 0.f;
    const float n1 = __shfl(dv, e1s) * __shfl(dv, e1d);   // full wave active
    const float n2 = __shfl(dv, e2s) * __shfl(dv, e2d);
#pragma unroll
    for (int c = 0; c < CC; c++) atomicAdd(&agg[e1d * 11 + c], hsA[wv][e1s][c] * n1);
#pragma unroll
    for (int c = 0; c < CC; c++) atomicAdd(&agg[e2d * 11 + c], hsA[wv][e2s][c] * n2);

    __syncthreads();  // B0: attL/asgL staged (cross-wave); agg done (intra-wave)

    // ---- per-node gcn + cross attention ----
    float gcn[CC], ax[CC];
    const int p = lane;
    if (p < SS) {
        float dp2 = dv * dv;
#pragma unroll
        for (int c = 0; c < CC; c++) gcn[c] = agg[p * 11 + c] + hsA[wv][p][c] * dp2 + convb[c];
#pragma unroll
        for (int c = 0; c < CC; c++) ax[c] = 0.f;
#pragma unroll 5
        for (int s = 0; s < SS; ++s) {
            float a = attL[p][s];
#pragma unroll
            for (int c = 0; c < CC; c++) ax[c] = fmaf(a, hsA[wv][s][10 + c], ax[c]);
        }
        if (isResp) {
#pragma unroll
            for (int c = 0; c < CC; c++) { srS[p][c] = gcn[c]; xuS[p][c] = ax[c]; }
        }
    }
    __syncthreads();  // B1: srS/xuS visible to utterance waves

    // ---- mpm x2 for utterance waves (resp data from LDS, own data in regs) ----
    if (!isResp) {
#pragma unroll
        for (int which = 0; which < 2; ++which) {
            float h2[20];
            if (lane < SS) {
                float self[CC], cro[CC];
#pragma unroll
                for (int c = 0; c < CC; c++) {
                    self[c] = which ? srS[lane][c] : gcn[c];
                    cro[c] = which ? ax[c] : xuS[lane][c];
                }
                float num = 0.f, na = 0.f, nc2 = 0.f;
#pragma unroll
                for (int c = 0; c < CC; c++) {
                    float av = asgL[lane][c];
                    float a = av * self[c];
                    float cx = av * cro[c];
                    num = fmaf(a, cx, num);
                    na = fmaf(a, a, na);
                    nc2 = fmaf(cx, cx, nc2);
                }
                float cosv = num / fmaxf(sqrtf(na) * sqrtf(nc2), 1e-8f);
                float h1[20];
#pragma unroll
                for (int j = 0; j < 20; j++) h1[j] = fmaf(cosv, W1[j], b1[j]);
#pragma unroll
                for (int k = 0; k < CC; k++) {
                    float sv = self[k];
#pragma unroll
                    for (int j = 0; j < 20; j++) h1[j] = fmaf(sv, W1[(k + 1) * 20 + j], h1[j]);
                }
#pragma unroll
                for (int j = 0; j < 20; j++) h1[j] = fmaxf(h1[j], 0.f);
#pragma unroll
                for (int j = 0; j < 20; j++) {
                    float t = b2[j];
#pragma unroll
                    for (int k = 0; k < 20; k++) t = fmaf(h1[k], W2[k * 20 + j], t);
                    h2[j] = t;
                }
            } else {
#pragma unroll
                for (int j = 0; j < 20; j++) h2[j] = -1e30f;
            }
#pragma unroll
            for (int o = 32; o; o >>= 1) {       // after if/else join: uniform
#pragma unroll
                for (int j = 0; j < 20; j++) h2[j] = fmaxf(h2[j], __shfl_xor(h2[j], o));
            }
            if (lane == 0) {
                float* o = which ? grS[wv] : guS[wv];
#pragma unroll
                for (int j = 0; j < 20; j++) o[j] = h2[j];
            }
        }
    }
    __syncthreads();  // B2: guS/grS ready; aggA free for fsum reuse

    // ---- final FFN + reduce + sigmoid ----
    float* fsum = &aggA[0][0][0];
    float term = 0.f;
    if (tid < 200) {
        const int t = tid / 40, j = tid - t * 40;
        float hvv = fb1[j];
#pragma unroll
        for (int k = 0; k < 20; k++) {
            float u = guS[t][k], r = grS[t][k];
            hvv = fmaf(u, fW1[k * 40 + j], hvv);
            hvv = fmaf(r, fW1[(20 + k) * 40 + j], hvv);
            hvv = fmaf(u * r, fW1[(40 + k) * 40 + j], hvv);
            hvv = fmaf(fabsf(u - r), fW1[(60 + k) * 40 + j], hvv);
        }
        term = fmaxf(hvv, 0.f) * fW2[j];
    }
    if (tid < 256) fsum[tid] = term;
    __syncthreads();  // B3
    if (wv == 0) {
        float s = fsum[lane] + fsum[lane + 64] + fsum[lane + 128] + fsum[lane + 192];
#pragma unroll
        for (int o = 32; o; o >>= 1) s += __shfl_xor(s, o);
        if (lane == 0) out[b] = 1.f / (1.f + expf(-(s + (float)TT * fb2[0])));
    }
}

extern "C" void kernel_launch(void* const* d_in, const int* in_sizes, int n_in,
                              void* d_out, int out_size, void* d_ws, size_t ws_size,
                              hipStream_t stream) {
    (void)in_sizes; (void)n_in; (void)out_size; (void)ws_size;
    const int* ctx_tok = (const int*)d_in[0];
    const int* resp_tok = (const int*)d_in[1];
    const int* ctx_adj = (const int*)d_in[2];
    const int* resp_adj = (const int*)d_in[3];
    const float* emb = (const float*)d_in[4];
    const float* convW = (const float*)d_in[5];
    const float* convb = (const float*)d_in[6];
    const float* crossW = (const float*)d_in[7];
    const float* att = (const float*)d_in[8];
    const float* assign = (const float*)d_in[9];
    const float* mpW1 = (const float*)d_in[10];
    const float* mpb1 = (const float*)d_in[11];
    const float* mpW2 = (const float*)d_in[12];
    const float* mpb2 = (const float*)d_in[13];
    const float* fW1 = (const float*)d_in[14];
    const float* fb1 = (const float*)d_in[15];
    const float* fW2 = (const float*)d_in[16];
    const float* fb2 = (const float*)d_in[17];

    float* hvp = (float*)d_ws;  // [2][VOCAB][20] = 3.38 MB
    float* outf = (float*)d_out;

    hipLaunchKernelGGL(k_vocab, dim3((VOCAB + 63) / 64, 2), dim3(512), 0, stream,
                       emb, convW, crossW, hvp);
    hipLaunchKernelGGL(k_batch, dim3(BB), dim3(384), 0, stream,
                       ctx_tok, resp_tok, ctx_adj, resp_adj, hvp, convb, att, assign,
                       mpW1, mpb1, mpW2, mpb2, fW1, fb1, fW2, fb2, outf);
}

// Round 8
// 89.855 us; speedup vs baseline: 3.1152x; 1.0196x over previous
//
#include <hip/hip_runtime.h>
#include <math.h>

#define VOCAB 21128
#define DD 768
#define SS 50
#define TT 5
#define BB 512
#define EE 128
#define CC 10
#define V20 (VOCAB * 20)
#define NG 2560  // B*T utterance graphs

// ---------------- kernel 1: hvp[kh][21128][20] = emb[:, kh-half] @ W-half ----------------
// (unchanged from round 7)
__global__ __launch_bounds__(512) void k_vocab(const float* __restrict__ emb,
                                               const float* __restrict__ Wconv,
                                               const float* __restrict__ Wcross,
                                               float* __restrict__ hvp) {
    __shared__ float tile[8][64][21];
    const int wv = threadIdx.x >> 6, lane = threadIdx.x & 63;
    const int rowbase = blockIdx.x * 64;
    const int rsub = lane >> 2, m = lane & 3;

    float acc[20];
#pragma unroll
    for (int c = 0; c < 20; c++) acc[c] = 0.f;

    const int d0w = blockIdx.y * 384 + __builtin_amdgcn_readfirstlane(wv * 48);

    for (int chunk = 0; chunk < 3; ++chunk) {
        const int d0 = d0w + chunk * 16;
#pragma unroll
        for (int it = 0; it < 4; ++it) {
            int row = it * 16 + rsub;
            long r = rowbase + row;
            if (r >= VOCAB) r = VOCAB - 1;
            const float4 v = *(const float4*)(emb + r * DD + d0 + m * 4);
            tile[wv][row][m * 4 + 0] = v.x;
            tile[wv][row][m * 4 + 1] = v.y;
            tile[wv][row][m * 4 + 2] = v.z;
            tile[wv][row][m * 4 + 3] = v.w;
        }
#pragma unroll
        for (int d = 0; d < 16; ++d) {
            float e = tile[wv][lane][d];
            const float* wc = Wconv + (d0 + d) * 10;
            const float* wx = Wcross + (d0 + d) * 10;
#pragma unroll
            for (int c = 0; c < 10; c++) {
                acc[c] = fmaf(e, wc[c], acc[c]);
                acc[10 + c] = fmaf(e, wx[c], acc[10 + c]);
            }
        }
    }

    __syncthreads();
    float* pp = &tile[0][0][0];
#pragma unroll
    for (int c = 0; c < 20; c++) pp[wv * 1280 + lane * 20 + c] = acc[c];
    __syncthreads();
    float* outp = hvp + (long)blockIdx.y * V20;
    for (int i = threadIdx.x; i < 1280; i += 512) {
        int row = i / 20;
        long r = rowbase + row;
        if (r < VOCAB) {
            float s = 0.f;
#pragma unroll
            for (int w = 0; w < 8; ++w) s += pp[w * 1280 + i];
            outp[r * 20 + (i - row * 20)] = s;
        }
    }
}

// ---- shared per-wave GCN machinery (gather + degree + aggregate + gcn + cross) ----
__device__ __forceinline__ void wave_gcn(const int* __restrict__ tb,
                                         const int* __restrict__ ab,
                                         const float* __restrict__ hvp,
                                         const float* __restrict__ convb,
                                         const float* __restrict__ att,
                                         float (*hsL)[20], float* agg, int* dgW,
                                         int lane, float* gcn, float* ax) {
    const int e1s = ab[lane], e2s = ab[lane + 64];
    const int e1d = ab[EE + lane], e2d = ab[EE + lane + 64];
    const int myTok = (lane < SS) ? tb[lane] : 0;

    dgW[lane] = 0;
    atomicAdd(&dgW[e1d], 1);
    atomicAdd(&dgW[e2d], 1);

    // gather: UNIFORM 16 iters, shfl convergent (r7 fix)
#pragma unroll
    for (int it = 0; it < 16; ++it) {
        const int i = it * 64 + lane;
        int s = i / 20;
        const int c = i - s * 20;
        const int sc = (s < SS) ? s : (SS - 1);
        const int t = __shfl(myTok, sc);
        if (i < SS * 20)
            hsL[s][c] = hvp[(long)t * 20 + c] + hvp[V20 + (long)t * 20 + c];
    }

    float dv = 0.f;
    if (lane < SS) dv = rsqrtf((float)(dgW[lane] + 1));

    for (int i = lane; i < SS * CC; i += 64) agg[i] = 0.f;
    const float n1 = __shfl(dv, e1s) * __shfl(dv, e1d);
    const float n2 = __shfl(dv, e2s) * __shfl(dv, e2d);
#pragma unroll
    for (int c = 0; c < CC; c++) atomicAdd(&agg[e1d * 10 + c], hsL[e1s][c] * n1);
#pragma unroll
    for (int c = 0; c < CC; c++) atomicAdd(&agg[e2d * 10 + c], hsL[e2s][c] * n2);

    const int p = lane;
#pragma unroll
    for (int c = 0; c < CC; c++) { gcn[c] = 0.f; ax[c] = 0.f; }
    if (p < SS) {
        float dp2 = dv * dv;
#pragma unroll
        for (int c = 0; c < CC; c++) gcn[c] = agg[p * 10 + c] + hsL[p][c] * dp2 + convb[c];
        const float* arow = att + p * SS;  // per-lane 200B row, L1-resident (att = 10KB)
#pragma unroll 5
        for (int s = 0; s < SS; ++s) {
            float a = arow[s];
#pragma unroll
            for (int c = 0; c < CC; c++) ax[c] = fmaf(a, hsL[s][10 + c], ax[c]);
        }
    }
}

// ---------------- kernel 2a: response graphs -> srG/xuG [B][50][10] ----------------
__global__ __launch_bounds__(256) void k_resp(const int* __restrict__ rtok,
                                              const int* __restrict__ radj,
                                              const float* __restrict__ hvp,
                                              const float* __restrict__ convb,
                                              const float* __restrict__ att,
                                              float* __restrict__ srG,
                                              float* __restrict__ xuG) {
    __shared__ float hsL[4][SS][20];
    __shared__ float aggL[4][SS][CC];
    __shared__ int dgS[4][64];
    const int wv = threadIdx.x >> 6, lane = threadIdx.x & 63;
    const int b = blockIdx.x * 4 + wv;

    float gcn[CC], ax[CC];
    wave_gcn(rtok + (long)b * SS, radj + (long)b * 2 * EE, hvp, convb, att,
             hsL[wv], &aggL[wv][0][0], dgS[wv], lane, gcn, ax);

    if (lane < SS) {
#pragma unroll
        for (int c = 0; c < CC; c++) {
            srG[(long)b * 500 + lane * 10 + c] = gcn[c];
            xuG[(long)b * 500 + lane * 10 + c] = ax[c];
        }
    }
}

// ---------------- kernel 2b: utterance graphs + mpm x2 -> guG/grG [2560][20] ----------------
__global__ __launch_bounds__(256) void k_utt(const int* __restrict__ ctok,
                                             const int* __restrict__ cadj,
                                             const float* __restrict__ hvp,
                                             const float* __restrict__ convb,
                                             const float* __restrict__ att,
                                             const float* __restrict__ assign,
                                             const float* __restrict__ W1, const float* __restrict__ b1,
                                             const float* __restrict__ W2, const float* __restrict__ b2,
                                             const float* __restrict__ srG,
                                             const float* __restrict__ xuG,
                                             float* __restrict__ guG,
                                             float* __restrict__ grG) {
    __shared__ float hsL[4][SS][20];   // 16000 B
    __shared__ float h1L[4][SS][20];   // 16000 B (first 500 floats double as agg)
    __shared__ float W2T[20][21];      // 1680 B
    __shared__ float asgL[SS][CC];     // 2000 B
    __shared__ int dgS[4][64];         // 1024 B  -> 36.7 KB total, 4 blocks/CU
    const int tid = threadIdx.x;
    const int wv = tid >> 6, lane = tid & 63;
    const int g = blockIdx.x * 4 + wv;          // graph id in [0, 2560)
    const int b = g / TT;

    // stage block-shared weights once (ONLY barrier in the kernel)
    for (int i = tid; i < 400; i += 256) W2T[i % 20][i / 20] = W2[i];  // W2T[j][k] = W2[k*20+j]
    for (int i = tid; i < SS * CC; i += 256) asgL[i / CC][i % CC] = assign[i];
    __syncthreads();

    float gcn[CC], ax[CC];
    wave_gcn(ctok + (long)g * SS, cadj + (long)g * 2 * EE, hvp, convb, att,
             hsL[wv], &h1L[wv][0][0], dgS[wv], lane, gcn, ax);

    // resp features for this b (L2-hot: each row read by 5 utterances)
    const int p = lane;
    float srv[CC], xuv[CC];
    if (p < SS) {
#pragma unroll
        for (int c = 0; c < CC; c++) {
            srv[c] = srG[(long)b * 500 + p * 10 + c];
            xuv[c] = xuG[(long)b * 500 + p * 10 + c];
        }
    }

    // W2^T row for my j, held across both mpm passes
    const int j = lane % 20;   // lanes 60-63: grp 3 (idle in phase B)
    const int grp = lane / 20;
    float w2r[20];
#pragma unroll
    for (int k = 0; k < 20; k++) w2r[k] = W2T[j][k];

#pragma unroll
    for (int which = 0; which < 2; ++which) {
        // ---- phase A: per-node h1 -> wave-private LDS (lanes 0..49) ----
        if (p < SS) {
            float self[CC], cro[CC];
#pragma unroll
            for (int c = 0; c < CC; c++) {
                self[c] = which ? srv[c] : gcn[c];
                cro[c] = which ? ax[c] : xuv[c];
            }
            float num = 0.f, na = 0.f, nc2 = 0.f;
#pragma unroll
            for (int c = 0; c < CC; c++) {
                float av = asgL[p][c];
                float a = av * self[c];
                float cx = av * cro[c];
                num = fmaf(a, cx, num);
                na = fmaf(a, a, na);
                nc2 = fmaf(cx, cx, nc2);
            }
            float cosv = num / fmaxf(sqrtf(na) * sqrtf(nc2), 1e-8f);
            float h1[20];
#pragma unroll
            for (int q = 0; q < 20; q++) h1[q] = fmaf(cosv, W1[q], b1[q]);
#pragma unroll
            for (int k = 0; k < CC; k++) {
                float sv = self[k];
#pragma unroll
                for (int q = 0; q < 20; q++) h1[q] = fmaf(sv, W1[(k + 1) * 20 + q], h1[q]);
            }
#pragma unroll
            for (int q = 0; q < 20; q++) h1L[wv][p][q] = fmaxf(h1[q], 0.f);
        }
        // same-wave ds_write -> ds_read: program order, no barrier needed

        // ---- phase B: h2[j] = max_s sum_k h1[s][k]*W2T[j][k], lanes = (j,grp) ----
        float part = -1e30f;
        if (grp < 3) {
            const int s0 = grp * 17;
            const int s1 = (grp == 2) ? SS : (s0 + 17);
            for (int s = s0; s < s1; ++s) {
                float t = 0.f;
#pragma unroll
                for (int k = 0; k < 20; k++) t = fmaf(h1L[wv][s][k], w2r[k], t);
                part = fmaxf(part, t);
            }
        }
        // combine 3 groups -> lane j (convergent full-wave shfls)
        const float a0 = __shfl(part, j);
        const float a1 = __shfl(part, j + 20);
        const float a2 = __shfl(part, j + 40);
        if (lane < 20) {
            float h2 = fmaxf(fmaxf(a0, a1), a2) + b2[lane];
            (which ? grG : guG)[(long)g * 20 + lane] = h2;
        }
    }
}

// ---------------- kernel 3: final FFN + sum over T + sigmoid ----------------
__global__ __launch_bounds__(64) void k_final(const float* __restrict__ g_u, const float* __restrict__ g_r,
                                              const float* __restrict__ W1, const float* __restrict__ b1,
                                              const float* __restrict__ W2, const float* __restrict__ b2,
                                              float* __restrict__ out) {
    const int b = blockIdx.x, lane = threadIdx.x;
    float ssum = 0.f;
    for (int t = 0; t < TT; t++) {
        const float* gu = g_u + ((long)b * TT + t) * 20;
        const float* gr = g_r + ((long)b * TT + t) * 20;
        float feat[80];
#pragma unroll
        for (int k = 0; k < 20; k++) {
            float u = gu[k], r = gr[k];
            feat[k] = u;
            feat[20 + k] = r;
            feat[40 + k] = u * r;
            feat[60 + k] = fabsf(u - r);
        }
        if (lane < 40) {
            float hv = b1[lane];
#pragma unroll
            for (int k = 0; k < 80; k++) hv = fmaf(feat[k], W1[k * 40 + lane], hv);
            ssum += fmaxf(hv, 0.f) * W2[lane];
        }
    }
    for (int off = 32; off; off >>= 1) ssum += __shfl_xor(ssum, off);
    if (lane == 0) out[b] = 1.f / (1.f + expf(-(ssum + (float)TT * b2[0])));
}

extern "C" void kernel_launch(void* const* d_in, const int* in_sizes, int n_in,
                              void* d_out, int out_size, void* d_ws, size_t ws_size,
                              hipStream_t stream) {
    (void)in_sizes; (void)n_in; (void)out_size; (void)ws_size;
    const int* ctx_tok = (const int*)d_in[0];
    const int* resp_tok = (const int*)d_in[1];
    const int* ctx_adj = (const int*)d_in[2];
    const int* resp_adj = (const int*)d_in[3];
    const float* emb = (const float*)d_in[4];
    const float* convW = (const float*)d_in[5];
    const float* convb = (const float*)d_in[6];
    const float* crossW = (const float*)d_in[7];
    const float* att = (const float*)d_in[8];
    const float* assign = (const float*)d_in[9];
    const float* mpW1 = (const float*)d_in[10];
    const float* mpb1 = (const float*)d_in[11];
    const float* mpW2 = (const float*)d_in[12];
    const float* mpb2 = (const float*)d_in[13];
    const float* fW1 = (const float*)d_in[14];
    const float* fb1 = (const float*)d_in[15];
    const float* fW2 = (const float*)d_in[16];
    const float* fb2 = (const float*)d_in[17];

    float* ws = (float*)d_ws;
    float* hvp = ws;                    // [2][VOCAB][20] = 845,120
    float* srG = hvp + 2 * V20;         // 256,000
    float* xuG = srG + 256000;          // 256,000
    float* guG = xuG + 256000;          // 51,200
    float* grG = guG + 51200;           // 51,200
    float* outf = (float*)d_out;

    hipLaunchKernelGGL(k_vocab, dim3((VOCAB + 63) / 64, 2), dim3(512), 0, stream,
                       emb, convW, crossW, hvp);
    hipLaunchKernelGGL(k_resp, dim3(BB / 4), dim3(256), 0, stream,
                       resp_tok, resp_adj, hvp, convb, att, srG, xuG);
    hipLaunchKernelGGL(k_utt, dim3(NG / 4), dim3(256), 0, stream,
                       ctx_tok, ctx_adj, hvp, convb, att, assign,
                       mpW1, mpb1, mpW2, mpb2, srG, xuG, guG, grG);
    hipLaunchKernelGGL(k_final, dim3(BB), dim3(64), 0, stream,
                       guG, grG, fW1, fb1, fW2, fb2, outf);
}

// Round 9
// 86.231 us; speedup vs baseline: 3.2462x; 1.0420x over previous
//
#include <hip/hip_runtime.h>
#include <math.h>

#define VOCAB 21128
#define DD 768
#define SS 50
#define TT 5
#define BB 512
#define EE 128
#define CC 10
#define V20 (VOCAB * 20)
#define NG 2560  // B*T utterance graphs

// ---------------- kernel 1: hvp[kh][21128][20] = emb[:, kh-half] @ W-half ----------------
// (unchanged from round 8)
__global__ __launch_bounds__(512) void k_vocab(const float* __restrict__ emb,
                                               const float* __restrict__ Wconv,
                                               const float* __restrict__ Wcross,
                                               float* __restrict__ hvp) {
    __shared__ float tile[8][64][21];
    const int wv = threadIdx.x >> 6, lane = threadIdx.x & 63;
    const int rowbase = blockIdx.x * 64;
    const int rsub = lane >> 2, m = lane & 3;

    float acc[20];
#pragma unroll
    for (int c = 0; c < 20; c++) acc[c] = 0.f;

    const int d0w = blockIdx.y * 384 + __builtin_amdgcn_readfirstlane(wv * 48);

    for (int chunk = 0; chunk < 3; ++chunk) {
        const int d0 = d0w + chunk * 16;
#pragma unroll
        for (int it = 0; it < 4; ++it) {
            int row = it * 16 + rsub;
            long r = rowbase + row;
            if (r >= VOCAB) r = VOCAB - 1;
            const float4 v = *(const float4*)(emb + r * DD + d0 + m * 4);
            tile[wv][row][m * 4 + 0] = v.x;
            tile[wv][row][m * 4 + 1] = v.y;
            tile[wv][row][m * 4 + 2] = v.z;
            tile[wv][row][m * 4 + 3] = v.w;
        }
#pragma unroll
        for (int d = 0; d < 16; ++d) {
            float e = tile[wv][lane][d];
            const float* wc = Wconv + (d0 + d) * 10;
            const float* wx = Wcross + (d0 + d) * 10;
#pragma unroll
            for (int c = 0; c < 10; c++) {
                acc[c] = fmaf(e, wc[c], acc[c]);
                acc[10 + c] = fmaf(e, wx[c], acc[10 + c]);
            }
        }
    }

    __syncthreads();
    float* pp = &tile[0][0][0];
#pragma unroll
    for (int c = 0; c < 20; c++) pp[wv * 1280 + lane * 20 + c] = acc[c];
    __syncthreads();
    float* outp = hvp + (long)blockIdx.y * V20;
    for (int i = threadIdx.x; i < 1280; i += 512) {
        int row = i / 20;
        long r = rowbase + row;
        if (r < VOCAB) {
            float s = 0.f;
#pragma unroll
            for (int w = 0; w < 8; ++w) s += pp[w * 1280 + i];
            outp[r * 20 + (i - row * 20)] = s;
        }
    }
}

// ---- per-wave GCN: float4 gather, LDS-transposed att, padded LDS (stride 21/51) ----
__device__ __forceinline__ void wave_gcn(const int* __restrict__ tb,
                                         const int* __restrict__ ab,
                                         const float* __restrict__ hvp,
                                         const float* __restrict__ convb,
                                         const float (*attT)[51],   // LDS [50][51]
                                         float (*hsL)[21], float (*agg)[21], int* dgW,
                                         int lane, float* gcn, float* ax) {
    const int e1s = ab[lane], e2s = ab[lane + 64];
    const int e1d = ab[EE + lane], e2d = ab[EE + lane + 64];
    const int myTok = (lane < SS) ? tb[lane] : 0;

    dgW[lane] = 0;
    atomicAdd(&dgW[e1d], 1);
    atomicAdd(&dgW[e2d], 1);

    // gather: 50 rows x 20 floats = 250 float4 per K-half, cooperative, coalesced-ish.
    // row index via CONVERGENT clamped shfl (r7 lesson), store predicated.
    const float4* hv4 = (const float4*)hvp;
#pragma unroll
    for (int it = 0; it < 4; ++it) {
        const int idx = it * 64 + lane;
        int row = idx / 5;
        const int q = idx - row * 5;
        const int rowc = (row < SS) ? row : (SS - 1);
        const int t = __shfl(myTok, rowc);           // all 64 lanes execute
        if (idx < SS * 5) {
            const float4 a = hv4[(long)t * 5 + q];
            const float4 bq = hv4[(long)(VOCAB * 5) + (long)t * 5 + q];
            float* dst = &hsL[row][q * 4];
            dst[0] = a.x + bq.x; dst[1] = a.y + bq.y;
            dst[2] = a.z + bq.z; dst[3] = a.w + bq.w;
        }
    }

    float dv = 0.f;
    if (lane < SS) dv = rsqrtf((float)(dgW[lane] + 1));   // +1 self loop

    // zero agg cols 0..9 (stride-21 rows)
#pragma unroll
    for (int it = 0; it < 8; ++it) {
        const int i = it * 64 + lane;
        const int r = i / 10, c = i - r * 10;
        if (i < SS * 10) agg[r][c] = 0.f;
    }
    const float n1 = __shfl(dv, e1s) * __shfl(dv, e1d);   // full wave: convergent
    const float n2 = __shfl(dv, e2s) * __shfl(dv, e2d);
#pragma unroll
    for (int c = 0; c < CC; c++) atomicAdd(&agg[e1d][c], hsL[e1s][c] * n1);
#pragma unroll
    for (int c = 0; c < CC; c++) atomicAdd(&agg[e2d][c], hsL[e2s][c] * n2);

    const int p = lane;
#pragma unroll
    for (int c = 0; c < CC; c++) { gcn[c] = 0.f; ax[c] = 0.f; }
    if (p < SS) {
        const float dp2 = dv * dv;
#pragma unroll
        for (int c = 0; c < CC; c++) gcn[c] = agg[p][c] + hsL[p][c] * dp2 + convb[c];
#pragma unroll 5
        for (int s = 0; s < SS; ++s) {
            const float a = attT[s][p];   // stride 51: conflict-free across lanes
#pragma unroll
            for (int c = 0; c < CC; c++) ax[c] = fmaf(a, hsL[s][10 + c], ax[c]);
        }
    }
}

// ---------------- kernel 2a: response graphs -> srxu[B][50][20] (gcn||ax packed) ----------------
__global__ __launch_bounds__(128) void k_resp(const int* __restrict__ rtok,
                                              const int* __restrict__ radj,
                                              const float* __restrict__ hvp,
                                              const float* __restrict__ convb,
                                              const float* __restrict__ att,
                                              float* __restrict__ srxu) {
    __shared__ float attT[SS][51];
    __shared__ float hsL[2][SS][21];
    __shared__ float aggL[2][SS][21];
    __shared__ int dgS[2][64];
    const int tid = threadIdx.x, wv = tid >> 6, lane = tid & 63;
    const int b = blockIdx.x * 2 + wv;

    for (int i = tid; i < SS * SS; i += 128) { int p = i / SS, s = i - p * SS; attT[s][p] = att[i]; }
    __syncthreads();

    float gcn[CC], ax[CC];
    wave_gcn(rtok + (long)b * SS, radj + (long)b * 2 * EE, hvp, convb, attT,
             hsL[wv], aggL[wv], dgS[wv], lane, gcn, ax);

    if (lane < SS) {
        float* o = srxu + (long)b * 1000 + lane * 20;
#pragma unroll
        for (int c = 0; c < CC; c++) { o[c] = gcn[c]; o[10 + c] = ax[c]; }
    }
}

// ---------------- kernel 2b: utterance graphs + mpm x2 -> guG/grG [2560][20] ----------------
// 1280 blocks x 128 thr (2 waves, 1 graph/wave) = exactly 5 blocks/CU (31.4 KB LDS).
__global__ __launch_bounds__(128) void k_utt(const int* __restrict__ ctok,
                                             const int* __restrict__ cadj,
                                             const float* __restrict__ hvp,
                                             const float* __restrict__ convb,
                                             const float* __restrict__ att,
                                             const float* __restrict__ assign,
                                             const float* __restrict__ W1, const float* __restrict__ b1,
                                             const float* __restrict__ W2, const float* __restrict__ b2,
                                             const float* __restrict__ srxu,
                                             float* __restrict__ guG,
                                             float* __restrict__ grG) {
    __shared__ float attT[SS][51];     // 10200 B
    __shared__ float W2T[20][21];      // 1680 B
    __shared__ float asgL[SS][11];     // 2200 B
    __shared__ float hsL[2][SS][21];   // 8400 B
    __shared__ float h1L[2][SS][21];   // 8400 B (cols 0..9 double as agg, temporally disjoint)
    __shared__ int dgS[2][64];         // 512 B   -> 31392 B total, 5 blocks/CU
    const int tid = threadIdx.x, wv = tid >> 6, lane = tid & 63;
    const int g = blockIdx.x * 2 + wv;
    const int b = g / TT;

    for (int i = tid; i < SS * SS; i += 128) { int p = i / SS, s = i - p * SS; attT[s][p] = att[i]; }
    for (int i = tid; i < 400; i += 128) W2T[i % 20][i / 20] = W2[i];  // W2T[j][k] = W2[k*20+j]
    for (int i = tid; i < SS * CC; i += 128) asgL[i / CC][i % CC] = assign[i];
    __syncthreads();   // only barrier

    float gcn[CC], ax[CC];
    wave_gcn(ctok + (long)g * SS, cadj + (long)g * 2 * EE, hvp, convb, attT,
             hsL[wv], h1L[wv], dgS[wv], lane, gcn, ax);

    // resp features (packed, aligned float4 x5 per lane)
    const int p = lane;
    float srv[CC], xuv[CC];
#pragma unroll
    for (int c = 0; c < CC; c++) { srv[c] = 0.f; xuv[c] = 0.f; }
    if (p < SS) {
        const float4* sp4 = (const float4*)(srxu + (long)b * 1000 + p * 20);
        const float4 t0 = sp4[0], t1 = sp4[1], t2 = sp4[2], t3 = sp4[3], t4 = sp4[4];
        srv[0] = t0.x; srv[1] = t0.y; srv[2] = t0.z; srv[3] = t0.w;
        srv[4] = t1.x; srv[5] = t1.y; srv[6] = t1.z; srv[7] = t1.w;
        srv[8] = t2.x; srv[9] = t2.y;
        xuv[0] = t2.z; xuv[1] = t2.w;
        xuv[2] = t3.x; xuv[3] = t3.y; xuv[4] = t3.z; xuv[5] = t3.w;
        xuv[6] = t4.x; xuv[7] = t4.y; xuv[8] = t4.z; xuv[9] = t4.w;
    }

    // W2^T row for my j, held across both mpm passes
    const int j = lane % 20;
    const int grp = lane / 20;
    float w2r[20];
#pragma unroll
    for (int k = 0; k < 20; k++) w2r[k] = W2T[j][k];

#pragma unroll
    for (int which = 0; which < 2; ++which) {
        // ---- phase A: per-node h1 -> wave-private LDS (lanes 0..49) ----
        if (p < SS) {
            float self[CC], cro[CC];
#pragma unroll
            for (int c = 0; c < CC; c++) {
                self[c] = which ? srv[c] : gcn[c];
                cro[c] = which ? ax[c] : xuv[c];
            }
            float num = 0.f, na = 0.f, nc2 = 0.f;
#pragma unroll
            for (int c = 0; c < CC; c++) {
                float av = asgL[p][c];
                float a = av * self[c];
                float cx = av * cro[c];
                num = fmaf(a, cx, num);
                na = fmaf(a, a, na);
                nc2 = fmaf(cx, cx, nc2);
            }
            float cosv = num / fmaxf(sqrtf(na) * sqrtf(nc2), 1e-8f);
            float h1[20];
#pragma unroll
            for (int q = 0; q < 20; q++) h1[q] = fmaf(cosv, W1[q], b1[q]);
#pragma unroll
            for (int k = 0; k < CC; k++) {
                float sv = self[k];
#pragma unroll
                for (int q = 0; q < 20; q++) h1[q] = fmaf(sv, W1[(k + 1) * 20 + q], h1[q]);
            }
#pragma unroll
            for (int q = 0; q < 20; q++) h1L[wv][p][q] = fmaxf(h1[q], 0.f);
        }
        // same-wave ds_write -> ds_read: program order

        // ---- phase B: h2[j] = max_s sum_k h1[s][k]*W2T[j][k], lanes = (j,grp) ----
        float part = -1e30f;
        if (grp < 3) {
            const int s0 = grp * 17;
            const int s1 = (grp == 2) ? SS : (s0 + 17);
            for (int s = s0; s < s1; ++s) {
                float t = 0.f;
#pragma unroll
                for (int k = 0; k < 20; k++) t = fmaf(h1L[wv][s][k], w2r[k], t);
                part = fmaxf(part, t);
            }
        }
        const float a0 = __shfl(part, j);          // convergent full-wave shfls
        const float a1 = __shfl(part, j + 20);
        const float a2 = __shfl(part, j + 40);
        if (lane < 20) {
            float h2 = fmaxf(fmaxf(a0, a1), a2) + b2[lane];
            (which ? grG : guG)[(long)g * 20 + lane] = h2;
        }
    }
}

// ---------------- kernel 3: final FFN + sum over T + sigmoid ----------------
__global__ __launch_bounds__(64) void k_final(const float* __restrict__ g_u, const float* __restrict__ g_r,
                                              const float* __restrict__ W1, const float* __restrict__ b1,
                                              const float* __restrict__ W2, const float* __restrict__ b2,
                                              float* __restrict__ out) {
    const int b = blockIdx.x, lane = threadIdx.x;
    float ssum = 0.f;
    for (int t = 0; t < TT; t++) {
        const float* gu = g_u + ((long)b * TT + t) * 20;
        const float* gr = g_r + ((long)b * TT + t) * 20;
        float feat[80];
#pragma unroll
        for (int k = 0; k < 20; k++) {
            float u = gu[k], r = gr[k];
            feat[k] = u;
            feat[20 + k] = r;
            feat[40 + k] = u * r;
            feat[60 + k] = fabsf(u - r);
        }
        if (lane < 40) {
            float hv = b1[lane];
#pragma unroll
            for (int k = 0; k < 80; k++) hv = fmaf(feat[k], W1[k * 40 + lane], hv);
            ssum += fmaxf(hv, 0.f) * W2[lane];
        }
    }
    for (int off = 32; off; off >>= 1) ssum += __shfl_xor(ssum, off);
    if (lane == 0) out[b] = 1.f / (1.f + expf(-(ssum + (float)TT * b2[0])));
}

extern "C" void kernel_launch(void* const* d_in, const int* in_sizes, int n_in,
                              void* d_out, int out_size, void* d_ws, size_t ws_size,
                              hipStream_t stream) {
    (void)in_sizes; (void)n_in; (void)out_size; (void)ws_size;
    const int* ctx_tok = (const int*)d_in[0];
    const int* resp_tok = (const int*)d_in[1];
    const int* ctx_adj = (const int*)d_in[2];
    const int* resp_adj = (const int*)d_in[3];
    const float* emb = (const float*)d_in[4];
    const float* convW = (const float*)d_in[5];
    const float* convb = (const float*)d_in[6];
    const float* crossW = (const float*)d_in[7];
    const float* att = (const float*)d_in[8];
    const float* assign = (const float*)d_in[9];
    const float* mpW1 = (const float*)d_in[10];
    const float* mpb1 = (const float*)d_in[11];
    const float* mpW2 = (const float*)d_in[12];
    const float* mpb2 = (const float*)d_in[13];
    const float* fW1 = (const float*)d_in[14];
    const float* fb1 = (const float*)d_in[15];
    const float* fW2 = (const float*)d_in[16];
    const float* fb2 = (const float*)d_in[17];

    float* ws = (float*)d_ws;
    float* hvp = ws;                     // [2][VOCAB][20] = 845,120
    float* srxu = hvp + 2 * V20;         // [B][50][20]    = 512,000
    float* guG = srxu + (long)BB * 1000; // 51,200
    float* grG = guG + (long)NG * 20;    // 51,200
    float* outf = (float*)d_out;

    hipLaunchKernelGGL(k_vocab, dim3((VOCAB + 63) / 64, 2), dim3(512), 0, stream,
                       emb, convW, crossW, hvp);
    hipLaunchKernelGGL(k_resp, dim3(BB / 2), dim3(128), 0, stream,
                       resp_tok, resp_adj, hvp, convb, att, srxu);
    hipLaunchKernelGGL(k_utt, dim3(NG / 2), dim3(128), 0, stream,
                       ctx_tok, ctx_adj, hvp, convb, att, assign,
                       mpW1, mpb1, mpW2, mpb2, srxu, guG, grG);
    hipLaunchKernelGGL(k_final, dim3(BB), dim3(64), 0, stream,
                       guG, grG, fW1, fb1, fW2, fb2, outf);
}

// Round 10
// 79.224 us; speedup vs baseline: 3.5333x; 1.0884x over previous
//
#include <hip/hip_runtime.h>
#include <math.h>

#define VOCAB 21128
#define DD 768
#define SS 50
#define TT 5
#define BB 512
#define EE 128
#define CC 10
#define V20 (VOCAB * 20)
#define NG 2560   // utterance graphs; resp graphs are G in [NG, NG+512)
#define NALL 3072 // NG + BB

// ---------------- kernel 1: hvp[kh][21128][20] = emb[:, kh-half] @ W-half ----------------
// Change vs r9: ALL 12 float4 loads prefetched upfront (48 VGPR) so HBM latency is
// paid once, not per 16-d chunk. tile[wv] wave-private -> no barriers in main loop.
__global__ __launch_bounds__(512) void k_vocab(const float* __restrict__ emb,
                                               const float* __restrict__ Wconv,
                                               const float* __restrict__ Wcross,
                                               float* __restrict__ hvp) {
    __shared__ float tile[8][64][21];  // 43008 B -> 3 blocks/CU (VGPR caps waves anyway)
    const int wv = threadIdx.x >> 6, lane = threadIdx.x & 63;
    const int rowbase = blockIdx.x * 64;
    const int rsub = lane >> 2, m = lane & 3;

    const int d0w = blockIdx.y * 384 + __builtin_amdgcn_readfirstlane(wv * 48);

    // prefetch all 3 chunks x 4 rows
    float4 v[12];
#pragma unroll
    for (int ch = 0; ch < 3; ++ch) {
#pragma unroll
        for (int it = 0; it < 4; ++it) {
            int row = it * 16 + rsub;
            long r = rowbase + row;
            if (r >= VOCAB) r = VOCAB - 1;
            v[ch * 4 + it] = *(const float4*)(emb + r * DD + d0w + ch * 16 + m * 4);
        }
    }

    float acc[20];
#pragma unroll
    for (int c = 0; c < 20; c++) acc[c] = 0.f;

#pragma unroll
    for (int ch = 0; ch < 3; ++ch) {
        const int d0 = d0w + ch * 16;
#pragma unroll
        for (int it = 0; it < 4; ++it) {
            const int row = it * 16 + rsub;
            const float4 w = v[ch * 4 + it];
            tile[wv][row][m * 4 + 0] = w.x;
            tile[wv][row][m * 4 + 1] = w.y;
            tile[wv][row][m * 4 + 2] = w.z;
            tile[wv][row][m * 4 + 3] = w.w;
        }
        // same-wave ds_write -> ds_read: in-order DS pipe
#pragma unroll
        for (int d = 0; d < 16; ++d) {
            float e = tile[wv][lane][d];
            const float* wc = Wconv + (d0 + d) * 10;   // scalar addr -> s_load
            const float* wx = Wcross + (d0 + d) * 10;
#pragma unroll
            for (int c = 0; c < 10; c++) {
                acc[c] = fmaf(e, wc[c], acc[c]);
                acc[10 + c] = fmaf(e, wx[c], acc[10 + c]);
            }
        }
    }

    __syncthreads();
    float* pp = &tile[0][0][0];  // reuse as part[8][64][20] (10240 <= 10752 floats)
#pragma unroll
    for (int c = 0; c < 20; c++) pp[wv * 1280 + lane * 20 + c] = acc[c];
    __syncthreads();
    float* outp = hvp + (long)blockIdx.y * V20;
    for (int i = threadIdx.x; i < 1280; i += 512) {
        int row = i / 20;
        long r = rowbase + row;
        if (r < VOCAB) {
            float s = 0.f;
#pragma unroll
            for (int w = 0; w < 8; ++w) s += pp[w * 1280 + i];
            outp[r * 20 + (i - row * 20)] = s;
        }
    }
}

// ---------------- kernel 2: unified GCN for all 3072 graphs -> P[G][50][20] ----------------
// 768 blocks x 256 thr (4 waves, 1 graph/wave). One barrier (attT stage) then none.
// Split hcv/hcx with 16B-aligned rows: cross-att inner = 1 lane-read + 3 broadcast
// vector reads + 10 FMA per s (r9: 11 scalar b32).
__global__ __launch_bounds__(256) void k_gcn(const int* __restrict__ ctok,
                                             const int* __restrict__ cadj,
                                             const int* __restrict__ rtok,
                                             const int* __restrict__ radj,
                                             const float* __restrict__ hvp,
                                             const float* __restrict__ convb,
                                             const float* __restrict__ att,
                                             float* __restrict__ P) {
    __shared__ float attT[SS][51];      // 10200 B
    __shared__ float hcv[4][SS][12];    // 9600 B  (conv features, rows 48B-aligned)
    __shared__ float hcx[4][SS][12];    // 9600 B  (cross features)
    __shared__ float aggL[4][SS][11];   // 8800 B
    __shared__ int dgS[4][64];          // 1024 B  -> 39224 B, 4 blocks/CU
    const int tid = threadIdx.x, wv = tid >> 6, lane = tid & 63;
    const int G = blockIdx.x * 4 + wv;  // 0..3071

    for (int i = tid; i < SS * SS; i += 256) { int p = i / SS, s = i - p * SS; attT[s][p] = att[i]; }
    __syncthreads();   // only barrier

    const int* tb;
    const int* ab;
    if (G < NG) { tb = ctok + (long)G * SS; ab = cadj + (long)G * 2 * EE; }
    else        { int b = G - NG; tb = rtok + (long)b * SS; ab = radj + (long)b * 2 * EE; }

    const int e1s = ab[lane], e2s = ab[lane + 64];
    const int e1d = ab[EE + lane], e2d = ab[EE + lane + 64];
    const int myTok = (lane < SS) ? tb[lane] : 0;

    dgS[wv][lane] = 0;
    atomicAdd(&dgS[wv][e1d], 1);
    atomicAdd(&dgS[wv][e2d], 1);

    // gather -> split hcv/hcx (convergent clamped shfl, store predicated/switched)
    const float4* hv4 = (const float4*)hvp;
#pragma unroll
    for (int it = 0; it < 4; ++it) {
        const int idx = it * 64 + lane;
        int row = idx / 5;
        const int q = idx - row * 5;
        const int rowc = (row < SS) ? row : (SS - 1);
        const int t = __shfl(myTok, rowc);            // all 64 lanes execute
        if (idx < SS * 5) {
            const float4 a = hv4[(long)t * 5 + q];
            const float4 b = hv4[(long)(VOCAB * 5) + (long)t * 5 + q];
            const float4 w = make_float4(a.x + b.x, a.y + b.y, a.z + b.z, a.w + b.w);
            if (q == 0)      *(float4*)&hcv[wv][row][0] = w;
            else if (q == 1) *(float4*)&hcv[wv][row][4] = w;
            else if (q == 2) { hcv[wv][row][8] = w.x; hcv[wv][row][9] = w.y;
                               hcx[wv][row][0] = w.z; hcx[wv][row][1] = w.w; }
            else if (q == 3) { *(float2*)&hcx[wv][row][2] = make_float2(w.x, w.y);
                               *(float2*)&hcx[wv][row][4] = make_float2(w.z, w.w); }
            else             { *(float2*)&hcx[wv][row][6] = make_float2(w.x, w.y);
                               *(float2*)&hcx[wv][row][8] = make_float2(w.z, w.w); }
        }
    }

    float dv = 0.f;
    if (lane < SS) dv = rsqrtf((float)(dgS[wv][lane] + 1));   // +1 self loop

    float* aggW = &aggL[wv][0][0];
    for (int i = lane; i < SS * 11; i += 64) aggW[i] = 0.f;
    const float n1 = __shfl(dv, e1s) * __shfl(dv, e1d);       // full wave: convergent
    const float n2 = __shfl(dv, e2s) * __shfl(dv, e2d);
#pragma unroll
    for (int c = 0; c < CC; c++) atomicAdd(&aggW[e1d * 11 + c], hcv[wv][e1s][c] * n1);
#pragma unroll
    for (int c = 0; c < CC; c++) atomicAdd(&aggW[e2d * 11 + c], hcv[wv][e2s][c] * n2);

    const int p = lane;
    if (p < SS) {
        float gcn[CC], ax[CC];
        const float dp2 = dv * dv;
        // self term: aligned per-lane vector reads
        const float4 s0 = *(const float4*)&hcv[wv][p][0];
        const float4 s1 = *(const float4*)&hcv[wv][p][4];
        const float s8 = hcv[wv][p][8], s9 = hcv[wv][p][9];
        gcn[0] = aggW[p * 11 + 0] + s0.x * dp2 + convb[0];
        gcn[1] = aggW[p * 11 + 1] + s0.y * dp2 + convb[1];
        gcn[2] = aggW[p * 11 + 2] + s0.z * dp2 + convb[2];
        gcn[3] = aggW[p * 11 + 3] + s0.w * dp2 + convb[3];
        gcn[4] = aggW[p * 11 + 4] + s1.x * dp2 + convb[4];
        gcn[5] = aggW[p * 11 + 5] + s1.y * dp2 + convb[5];
        gcn[6] = aggW[p * 11 + 6] + s1.z * dp2 + convb[6];
        gcn[7] = aggW[p * 11 + 7] + s1.w * dp2 + convb[7];
        gcn[8] = aggW[p * 11 + 8] + s8 * dp2 + convb[8];
        gcn[9] = aggW[p * 11 + 9] + s9 * dp2 + convb[9];
#pragma unroll
        for (int c = 0; c < CC; c++) ax[c] = 0.f;
#pragma unroll 5
        for (int s = 0; s < SS; ++s) {
            const float a = attT[s][p];                       // lane-strided, conflict-free
            const float4 x0 = *(const float4*)&hcx[wv][s][0]; // uniform -> broadcast
            const float4 x1 = *(const float4*)&hcx[wv][s][4];
            const float2 x2 = *(const float2*)&hcx[wv][s][8];
            ax[0] = fmaf(a, x0.x, ax[0]); ax[1] = fmaf(a, x0.y, ax[1]);
            ax[2] = fmaf(a, x0.z, ax[2]); ax[3] = fmaf(a, x0.w, ax[3]);
            ax[4] = fmaf(a, x1.x, ax[4]); ax[5] = fmaf(a, x1.y, ax[5]);
            ax[6] = fmaf(a, x1.z, ax[6]); ax[7] = fmaf(a, x1.w, ax[7]);
            ax[8] = fmaf(a, x2.x, ax[8]); ax[9] = fmaf(a, x2.y, ax[9]);
        }
        // packed write: [gcn0-9 | ax0-9]
        float4* o4 = (float4*)(P + (long)G * 1000 + p * 20);
        o4[0] = make_float4(gcn[0], gcn[1], gcn[2], gcn[3]);
        o4[1] = make_float4(gcn[4], gcn[5], gcn[6], gcn[7]);
        o4[2] = make_float4(gcn[8], gcn[9], ax[0], ax[1]);
        o4[3] = make_float4(ax[2], ax[3], ax[4], ax[5]);
        o4[4] = make_float4(ax[6], ax[7], ax[8], ax[9]);
    }
}

// ---------------- kernel 3: mpm, one wave per (g, which) = 5120 waves ----------------
// which=0 (g_u): self = ctx gcn (Pc cols 0-9), cross = u_cross = resp ax (Pr cols 10-19)
// which=1 (g_r): self = resp gcn (Pr cols 0-9), cross = r_cross = ctx ax (Pc cols 10-19)
__global__ __launch_bounds__(256) void k_mpm(const float* __restrict__ P,
                                             const float* __restrict__ assign,
                                             const float* __restrict__ W1, const float* __restrict__ b1,
                                             const float* __restrict__ W2, const float* __restrict__ b2,
                                             float* __restrict__ guG,
                                             float* __restrict__ grG) {
    __shared__ float W2T[20][21];      // 1680 B
    __shared__ float asgL[SS][11];     // 2200 B
    __shared__ float h1L[4][SS][20];   // 16000 B -> 19880 B, 8 blocks/CU
    const int tid = threadIdx.x, wv = tid >> 6, lane = tid & 63;
    const int wid = blockIdx.x * 4 + wv;
    const int g = wid >> 1, which = wid & 1;
    const int b = g / TT;

    for (int i = tid; i < 400; i += 256) W2T[i % 20][i / 20] = W2[i];  // W2T[j][k] = W2[k*20+j]
    for (int i = tid; i < SS * CC; i += 256) asgL[i / CC][i % CC] = assign[i];
    __syncthreads();   // only barrier

    const float* Pc = P + (long)g * 1000;
    const float* Pr = P + (long)(NG + b) * 1000;
    const float* selfP = which ? Pr : Pc;
    const float* croP  = which ? Pc : Pr;

    const int p = lane;
    float self[CC], cro[CC];
    if (p < SS) {
        const float4* s4 = (const float4*)(selfP + p * 20);
        const float4 a0 = s4[0], a1 = s4[1], a2 = s4[2];
        self[0] = a0.x; self[1] = a0.y; self[2] = a0.z; self[3] = a0.w;
        self[4] = a1.x; self[5] = a1.y; self[6] = a1.z; self[7] = a1.w;
        self[8] = a2.x; self[9] = a2.y;
        const float4* c4 = (const float4*)(croP + p * 20);
        const float4 b0 = c4[2], b1q = c4[3], b2q = c4[4];
        cro[0] = b0.z; cro[1] = b0.w;
        cro[2] = b1q.x; cro[3] = b1q.y; cro[4] = b1q.z; cro[5] = b1q.w;
        cro[6] = b2q.x; cro[7] = b2q.y; cro[8] = b2q.z; cro[9] = b2q.w;
    }

    // W2^T row for my j
    const int j = lane % 20;
    const int grp = lane / 20;
    float w2r[20];
#pragma unroll
    for (int k = 0; k < 20; k++) w2r[k] = W2T[j][k];

    // ---- phase A: per-node cos + h1 -> wave-private LDS ----
    if (p < SS) {
        float num = 0.f, na = 0.f, nc2 = 0.f;
#pragma unroll
        for (int c = 0; c < CC; c++) {
            float av = asgL[p][c];
            float a = av * self[c];
            float cx = av * cro[c];
            num = fmaf(a, cx, num);
            na = fmaf(a, a, na);
            nc2 = fmaf(cx, cx, nc2);
        }
        float cosv = num / fmaxf(sqrtf(na) * sqrtf(nc2), 1e-8f);
        float h1[20];
#pragma unroll
        for (int q = 0; q < 20; q++) h1[q] = fmaf(cosv, W1[q], b1[q]);
#pragma unroll
        for (int k = 0; k < CC; k++) {
            float sv = self[k];
#pragma unroll
            for (int q = 0; q < 20; q++) h1[q] = fmaf(sv, W1[(k + 1) * 20 + q], h1[q]);
        }
        float4* hw = (float4*)&h1L[wv][p][0];
        hw[0] = make_float4(fmaxf(h1[0], 0.f), fmaxf(h1[1], 0.f), fmaxf(h1[2], 0.f), fmaxf(h1[3], 0.f));
        hw[1] = make_float4(fmaxf(h1[4], 0.f), fmaxf(h1[5], 0.f), fmaxf(h1[6], 0.f), fmaxf(h1[7], 0.f));
        hw[2] = make_float4(fmaxf(h1[8], 0.f), fmaxf(h1[9], 0.f), fmaxf(h1[10], 0.f), fmaxf(h1[11], 0.f));
        hw[3] = make_float4(fmaxf(h1[12], 0.f), fmaxf(h1[13], 0.f), fmaxf(h1[14], 0.f), fmaxf(h1[15], 0.f));
        hw[4] = make_float4(fmaxf(h1[16], 0.f), fmaxf(h1[17], 0.f), fmaxf(h1[18], 0.f), fmaxf(h1[19], 0.f));
    }
    // same-wave ds_write -> ds_read: in-order DS pipe, no barrier

    // ---- phase B: h2[j] = max_s sum_k h1[s][k]*W2T[j][k] ----
    float part = -1e30f;
    if (grp < 3) {
        const int s0 = grp * 17;
        const int s1 = (grp == 2) ? SS : (s0 + 17);
        for (int s = s0; s < s1; ++s) {
            const float* hr = &h1L[wv][s][0];   // uniform -> broadcast b128 x5
            float t = 0.f;
#pragma unroll
            for (int k = 0; k < 20; k++) t = fmaf(hr[k], w2r[k], t);
            part = fmaxf(part, t);
        }
    }
    const float a0 = __shfl(part, j);           // convergent full-wave shfls
    const float a1 = __shfl(part, j + 20);
    const float a2 = __shfl(part, j + 40);
    if (lane < 20) {
        float h2 = fmaxf(fmaxf(a0, a1), a2) + b2[lane];
        (which ? grG : guG)[(long)g * 20 + lane] = h2;
    }
}

// ---------------- kernel 4: final FFN + sum over T + sigmoid ----------------
__global__ __launch_bounds__(64) void k_final(const float* __restrict__ g_u, const float* __restrict__ g_r,
                                              const float* __restrict__ W1, const float* __restrict__ b1,
                                              const float* __restrict__ W2, const float* __restrict__ b2,
                                              float* __restrict__ out) {
    const int b = blockIdx.x, lane = threadIdx.x;
    float ssum = 0.f;
    for (int t = 0; t < TT; t++) {
        const float* gu = g_u + ((long)b * TT + t) * 20;
        const float* gr = g_r + ((long)b * TT + t) * 20;
        float feat[80];
#pragma unroll
        for (int k = 0; k < 20; k++) {
            float u = gu[k], r = gr[k];
            feat[k] = u;
            feat[20 + k] = r;
            feat[40 + k] = u * r;
            feat[60 + k] = fabsf(u - r);
        }
        if (lane < 40) {
            float hv = b1[lane];
#pragma unroll
            for (int k = 0; k < 80; k++) hv = fmaf(feat[k], W1[k * 40 + lane], hv);
            ssum += fmaxf(hv, 0.f) * W2[lane];
        }
    }
    for (int off = 32; off; off >>= 1) ssum += __shfl_xor(ssum, off);
    if (lane == 0) out[b] = 1.f / (1.f + expf(-(ssum + (float)TT * b2[0])));
}

extern "C" void kernel_launch(void* const* d_in, const int* in_sizes, int n_in,
                              void* d_out, int out_size, void* d_ws, size_t ws_size,
                              hipStream_t stream) {
    (void)in_sizes; (void)n_in; (void)out_size; (void)ws_size;
    const int* ctx_tok = (const int*)d_in[0];
    const int* resp_tok = (const int*)d_in[1];
    const int* ctx_adj = (const int*)d_in[2];
    const int* resp_adj = (const int*)d_in[3];
    const float* emb = (const float*)d_in[4];
    const float* convW = (const float*)d_in[5];
    const float* convb = (const float*)d_in[6];
    const float* crossW = (const float*)d_in[7];
    const float* att = (const float*)d_in[8];
    const float* assign = (const float*)d_in[9];
    const float* mpW1 = (const float*)d_in[10];
    const float* mpb1 = (const float*)d_in[11];
    const float* mpW2 = (const float*)d_in[12];
    const float* mpb2 = (const float*)d_in[13];
    const float* fW1 = (const float*)d_in[14];
    const float* fb1 = (const float*)d_in[15];
    const float* fW2 = (const float*)d_in[16];
    const float* fb2 = (const float*)d_in[17];

    float* ws = (float*)d_ws;
    float* hvp = ws;                       // [2][VOCAB][20]   = 845,120 floats
    float* P = hvp + 2 * V20;              // [3072][50][20]   = 3,072,000
    float* guG = P + (long)NALL * 1000;    // 51,200
    float* grG = guG + (long)NG * 20;      // 51,200
    float* outf = (float*)d_out;

    hipLaunchKernelGGL(k_vocab, dim3((VOCAB + 63) / 64, 2), dim3(512), 0, stream,
                       emb, convW, crossW, hvp);
    hipLaunchKernelGGL(k_gcn, dim3(NALL / 4), dim3(256), 0, stream,
                       ctx_tok, ctx_adj, resp_tok, resp_adj, hvp, convb, att, P);
    hipLaunchKernelGGL(k_mpm, dim3(NG * 2 / 4), dim3(256), 0, stream,
                       P, assign, mpW1, mpb1, mpW2, mpb2, guG, grG);
    hipLaunchKernelGGL(k_final, dim3(BB), dim3(64), 0, stream,
                       guG, grG, fW1, fb1, fW2, fb2, outf);
}